// Round 9
// baseline (333.617 us; speedup 1.0000x reference)
//
#include <hip/hip_runtime.h>
#include <math.h>

#define N_ 4096

// ---------------- workspace float offsets -----------------------------------
static constexpr size_t OFF_STATS0 = 0;        // [4][64][2]
static constexpr size_t OFF_STATS1 = 512;      // [4][128][2] (memset 1536)
static constexpr size_t OFF_HP0    = 2048;     // [16][4096][32]; ELU aliases
static constexpr size_t OFF_ELU    = 2048;     // [4][4096][128]
static constexpr size_t OFF_SS0    = 2099200;
static constexpr size_t OFF_SD0    = 2164736;
static constexpr size_t OFF_RUNS0  = 2230272;  // u64[16][4096]
static constexpr size_t OFF_SV0    = 2361344;
static constexpr size_t OFF_PM0    = 2426880;
static constexpr size_t OFF_EP0    = 2492416;
static constexpr size_t OFF_EN0    = 2557952;
static constexpr size_t OFF_CPP0   = 2623488;  // [16][4097] scalar count prefixes
static constexpr size_t OFF_CPN0   = 2689040;
static constexpr size_t OFF_RAWP0  = 2754592;  // [16][256][32]
static constexpr size_t OFF_RAWN0  = 2885664;
static constexpr size_t OFF_BP0    = 3016736;  // [16][257][32]
static constexpr size_t OFF_BN0    = 3148320;
static constexpr size_t OFF_TPP0   = 3279904;  // [16][4097][32]
static constexpr size_t OFF_TPN0   = 5377568;  // ends 7475232
// ---- layer1 aliases TPP0/TPN0 region (dead after keval0) ----
static constexpr size_t OFF_HP1    = 3279904;  // [4][4096][64]
static constexpr size_t OFF_SS1    = 4328480;
static constexpr size_t OFF_SD1    = 4344864;
static constexpr size_t OFF_RUNS1  = 4361248;  // u64[4][4096]
static constexpr size_t OFF_SV1    = 4394016;
static constexpr size_t OFF_PM1    = 4410400;
static constexpr size_t OFF_EP1    = 4426784;
static constexpr size_t OFF_EN1    = 4443168;
static constexpr size_t OFF_CPP1   = 4459552;  // [4][4097]
static constexpr size_t OFF_CPN1   = 4475940;
static constexpr size_t OFF_RAWP1  = 4492328;  // [4][256][64]
static constexpr size_t OFF_RAWN1  = 4557864;
static constexpr size_t OFF_BP1    = 4623400;  // [4][257][64]
static constexpr size_t OFF_BN1    = 4689192;
static constexpr size_t OFF_TPP1   = 4754984;  // [4][4097][64]
static constexpr size_t OFF_TPN1   = 5803816;  // end 6852648 floats ~27.4 MB

__device__ __forceinline__ unsigned f2s(float f){
  unsigned u=__float_as_uint(f);
  return u^((u&0x80000000u)?0xFFFFFFFFu:0x80000000u);
}
__device__ __forceinline__ float s2f(unsigned s){
  unsigned u=(s&0x80000000u)?(s^0x80000000u):~s;
  return __uint_as_float(u);
}

// ---------- partial stats for layer0 input (coalesced) -----------------------
template<int C>
__global__ void kstats(const float* __restrict__ x, float* __restrict__ stats){
  int blk=blockIdx.x; int b=blk>>5, seg=blk&31;
  int tid=threadIdx.x;
  const int RPT=256/C;
  const int IT=128/RPT;
  int c=tid%C, rl=tid/C;
  const float* xb=x+(size_t)b*N_*C;
  float s1=0.f,s2=0.f;
  int r0=seg*128+rl;
  for(int i=0;i<IT;i++){
    float v=xb[(size_t)(r0+i*RPT)*C+c];
    s1+=v;s2+=v*v;
  }
  __shared__ float sh1[256],sh2[256];
  sh1[tid]=s1;sh2[tid]=s2;__syncthreads();
  if(tid<C){
    float a1=0.f,a2=0.f;
    for(int g=0;g<RPT;g++){a1+=sh1[g*C+tid];a2+=sh2[g*C+tid];}
    atomicAdd(&stats[(size_t)(b*C+tid)*2+0],a1);
    atomicAdd(&stats[(size_t)(b*C+tid)*2+1],a2);
  }
}

// ---------- layer0 projection; 2 rows/thread, h wave-uniform (LDS broadcast) -
__global__ void __launch_bounds__(256) kproj0(
                       const float* __restrict__ x, const float* __restrict__ stats,
                       const float* __restrict__ w0, const float* __restrict__ asrc,
                       const float* __restrict__ adst, float* __restrict__ hp,
                       float* __restrict__ ss, float* __restrict__ sd){
  __shared__ float4 w4[2048];
  __shared__ float4 av4[64];
  __shared__ float mean[64],rstd[64];
  int tid=threadIdx.x;
  const float4* wg=(const float4*)w0;
  for(int i=tid;i<2048;i+=256) w4[i]=wg[i];
  if(tid<32) av4[tid]=((const float4*)asrc)[tid];
  else if(tid<64) av4[tid]=((const float4*)adst)[tid-32];
  int gid=blockIdx.x*256+tid;              // 0..32767
  int b=gid>>13, h=(gid>>11)&3, n0=gid&2047;  // rows n0, n0+2048; h wave-uniform
  if(tid<64){
    float s1=stats[(size_t)(b*64+tid)*2+0],s2=stats[(size_t)(b*64+tid)*2+1];
    float mu=s1*(1.0f/N_);
    float var=s2*(1.0f/N_)-mu*mu;
    mean[tid]=mu; rstd[tid]=rsqrtf(var+1e-5f);
  }
  __syncthreads();
  const float4* hA4=(const float4*)(x+((size_t)(b*N_+n0))*64);
  const float4* hB4=(const float4*)(x+((size_t)(b*N_+n0+2048))*64);
  float4 accA[8],accB[8];
  #pragma unroll
  for(int q=0;q<8;q++){accA[q]=make_float4(0.f,0.f,0.f,0.f);accB[q]=make_float4(0.f,0.f,0.f,0.f);}
  #pragma unroll
  for(int ch=0;ch<4;ch++){
    float4 tA[4],tB[4];
    #pragma unroll
    for(int j=0;j<4;j++){tA[j]=hA4[ch*4+j];tB[j]=hB4[ch*4+j];}
    #pragma unroll
    for(int j=0;j<4;j++){
      int d0=ch*16+j*4;
      float hvA[4],hvB[4];
      hvA[0]=(tA[j].x-mean[d0+0])*rstd[d0+0]; hvB[0]=(tB[j].x-mean[d0+0])*rstd[d0+0];
      hvA[1]=(tA[j].y-mean[d0+1])*rstd[d0+1]; hvB[1]=(tB[j].y-mean[d0+1])*rstd[d0+1];
      hvA[2]=(tA[j].z-mean[d0+2])*rstd[d0+2]; hvB[2]=(tB[j].z-mean[d0+2])*rstd[d0+2];
      hvA[3]=(tA[j].w-mean[d0+3])*rstd[d0+3]; hvB[3]=(tB[j].w-mean[d0+3])*rstd[d0+3];
      #pragma unroll
      for(int dd=0;dd<4;dd++){
        float a=hvA[dd],bb=hvB[dd];
        #pragma unroll
        for(int q=0;q<8;q++){
          float4 wv=w4[(h*64+d0+dd)*8+q];
          accA[q].x+=a*wv.x;accA[q].y+=a*wv.y;accA[q].z+=a*wv.z;accA[q].w+=a*wv.w;
          accB[q].x+=bb*wv.x;accB[q].y+=bb*wv.y;accB[q].z+=bb*wv.z;accB[q].w+=bb*wv.w;
        }
      }
    }
  }
  float ssA=0.f,sdA=0.f,ssB=0.f,sdB=0.f;
  #pragma unroll
  for(int q=0;q<8;q++){
    float4 a1=av4[h*8+q],a2=av4[32+h*8+q];
    ssA+=accA[q].x*a1.x+accA[q].y*a1.y+accA[q].z*a1.z+accA[q].w*a1.w;
    sdA+=accA[q].x*a2.x+accA[q].y*a2.y+accA[q].z*a2.z+accA[q].w*a2.w;
    ssB+=accB[q].x*a1.x+accB[q].y*a1.y+accB[q].z*a1.z+accB[q].w*a1.w;
    sdB+=accB[q].x*a2.x+accB[q].y*a2.y+accB[q].z*a2.z+accB[q].w*a2.w;
  }
  int p=b*4+h;
  float4* oA=(float4*)(hp+((size_t)p*N_+n0)*32);
  float4* oB=(float4*)(hp+((size_t)p*N_+n0+2048)*32);
  #pragma unroll
  for(int q=0;q<8;q++){oA[q]=accA[q];oB[q]=accB[q];}
  ss[(size_t)p*N_+n0]=ssA; sd[(size_t)p*N_+n0]=sdA;
  ss[(size_t)p*N_+n0+2048]=ssB; sd[(size_t)p*N_+n0+2048]=sdB;
}

// ---------- layer1 projection; 2 rows/thread, q4 wave-uniform ----------------
__global__ void __launch_bounds__(256) kproj1(
                       const float* __restrict__ x, const float* __restrict__ stats,
                       const float* __restrict__ w1, const float* __restrict__ asrc,
                       const float* __restrict__ adst, float* __restrict__ hp,
                       float* __restrict__ ss, float* __restrict__ sd){
  __shared__ float4 w4[2048];
  __shared__ float wa[128],wd[128],mean[128],rstd[128];
  int tid=threadIdx.x;
  const float4* wg=(const float4*)w1;
  for(int i=tid;i<2048;i+=256) w4[i]=wg[i];
  int gid=blockIdx.x*256+tid;              // 0..32767
  int b=gid>>13, q4=(gid>>11)&3, n0=gid&2047;
  if(tid<128){
    float s1a=0.f,s2a=0.f;
    for(int k=0;k<64;k++){float wv=w1[tid*64+k];s1a+=wv*asrc[k];s2a+=wv*adst[k];}
    wa[tid]=s1a;wd[tid]=s2a;
    float s1=stats[(size_t)(b*128+tid)*2+0],s2=stats[(size_t)(b*128+tid)*2+1];
    float mu=s1*(1.0f/N_);
    float var=s2*(1.0f/N_)-mu*mu;
    mean[tid]=mu; rstd[tid]=rsqrtf(var+1e-5f);
  }
  __syncthreads();
  const float4* hA4=(const float4*)(x+((size_t)(b*N_+n0))*128);
  const float4* hB4=(const float4*)(x+((size_t)(b*N_+n0+2048))*128);
  float4 accA[4],accB[4];
  #pragma unroll
  for(int q=0;q<4;q++){accA[q]=make_float4(0.f,0.f,0.f,0.f);accB[q]=make_float4(0.f,0.f,0.f,0.f);}
  float s1A=0.f,s2A=0.f,s1B=0.f,s2B=0.f;
  #pragma unroll
  for(int ch=0;ch<8;ch++){
    float4 tA[4],tB[4];
    #pragma unroll
    for(int j=0;j<4;j++){tA[j]=hA4[ch*4+j];tB[j]=hB4[ch*4+j];}
    #pragma unroll
    for(int j=0;j<4;j++){
      int d0=ch*16+j*4;
      float hvA[4],hvB[4];
      hvA[0]=(tA[j].x-mean[d0+0])*rstd[d0+0]; hvB[0]=(tB[j].x-mean[d0+0])*rstd[d0+0];
      hvA[1]=(tA[j].y-mean[d0+1])*rstd[d0+1]; hvB[1]=(tB[j].y-mean[d0+1])*rstd[d0+1];
      hvA[2]=(tA[j].z-mean[d0+2])*rstd[d0+2]; hvB[2]=(tB[j].z-mean[d0+2])*rstd[d0+2];
      hvA[3]=(tA[j].w-mean[d0+3])*rstd[d0+3]; hvB[3]=(tB[j].w-mean[d0+3])*rstd[d0+3];
      #pragma unroll
      for(int dd=0;dd<4;dd++){
        float a=hvA[dd],bb=hvB[dd]; int d=d0+dd;
        s1A+=a*wa[d]; s2A+=a*wd[d];
        s1B+=bb*wa[d]; s2B+=bb*wd[d];
        #pragma unroll
        for(int q=0;q<4;q++){
          float4 wv=w4[d*16+q4*4+q];
          accA[q].x+=a*wv.x;accA[q].y+=a*wv.y;accA[q].z+=a*wv.z;accA[q].w+=a*wv.w;
          accB[q].x+=bb*wv.x;accB[q].y+=bb*wv.y;accB[q].z+=bb*wv.z;accB[q].w+=bb*wv.w;
        }
      }
    }
  }
  float4* oA=(float4*)(hp+((size_t)(b*N_+n0))*64+q4*16);
  float4* oB=(float4*)(hp+((size_t)(b*N_+n0+2048))*64+q4*16);
  #pragma unroll
  for(int q=0;q<4;q++){oA[q]=accA[q];oB[q]=accB[q];}
  if(q4==0){
    ss[(size_t)b*N_+n0]=s1A; sd[(size_t)b*N_+n0]=s2A;
    ss[(size_t)b*N_+n0+2048]=s1B; sd[(size_t)b*N_+n0+2048]=s2B;
  }
}

// ---------- sort runs of 1024 (packed u64 = key<<32 | orig_idx) --------------
__global__ void __launch_bounds__(256) ksort_runs(const float* __restrict__ sdst,
                                                  unsigned long long* __restrict__ runs){
  __shared__ unsigned long long sm[1024];
  int p=blockIdx.x>>2, run=blockIdx.x&3;
  int tid=threadIdx.x;
  const float* s=sdst+(size_t)p*N_+run*1024;
  for(int l=tid;l<1024;l+=256){
    unsigned key=f2s(s[l]);
    sm[l]=((unsigned long long)key<<32)|(unsigned)(run*1024+l);
  }
  for(unsigned k=2;k<=1024u;k<<=1)
    for(unsigned j=k>>1;j>0;j>>=1){
      __syncthreads();
      for(unsigned t=tid;t<512u;t+=256u){
        unsigned i=((t&~(j-1))<<1)|(t&(j-1));
        unsigned q=i|j;
        bool up=((i&k)==0);
        unsigned long long a=sm[i],b=sm[q];
        if((a>b)==up){sm[i]=b;sm[q]=a;}
      }
    }
  __syncthreads();
  unsigned long long* rg=runs+(size_t)p*N_+run*1024;
  for(int l=tid;l<1024;l+=256) rg[l]=sm[l];
}

// ---------- merge 4 sorted runs by rank (binary search in LDS) ---------------
__global__ void __launch_bounds__(1024) kmerge(const unsigned long long* __restrict__ runs,
    float* __restrict__ sv, unsigned* __restrict__ perm,
    float* __restrict__ eP, float* __restrict__ eN){
  __shared__ unsigned long long sm[4096];
  int p=blockIdx.x>>2, cg=blockIdx.x&3;
  int tid=threadIdx.x;
  const unsigned long long* rg=runs+(size_t)p*N_;
  for(int l=tid;l<4096;l+=1024) sm[l]=rg[l];
  __syncthreads();
  unsigned long long e=sm[cg*1024+tid];
  int rank=tid;
  #pragma unroll
  for(int o=0;o<4;o++){
    if(o==cg) continue;
    const unsigned long long* base=sm+o*1024;
    int lo=0,hi=1024;
    while(lo<hi){int mid=(lo+hi)>>1; if(base[mid]<e) lo=mid+1; else hi=mid;}
    rank+=lo;
  }
  unsigned long long mk=sm[1023];
  if(sm[2047]>mk) mk=sm[2047];
  if(sm[3071]>mk) mk=sm[3071];
  if(sm[4095]>mk) mk=sm[4095];
  float m=s2f((unsigned)(mk>>32));
  float v=s2f((unsigned)(e>>32));
  size_t o=(size_t)p*N_+rank;
  sv[o]=v;
  perm[o]=(unsigned)(e&0xffffffffu);
  eP[o]=expf(v-m);
  eN[o]=expf(0.2f*(v-m));
}

// ---------- layer0 relative tables: 2 chunks per wave, width-32 rows ---------
__global__ void __launch_bounds__(256) ktables0(const unsigned* __restrict__ perm,
    const float* __restrict__ eP, const float* __restrict__ eN,
    const float* __restrict__ hp, float* __restrict__ TPP, float* __restrict__ TPN,
    float* __restrict__ rawP, float* __restrict__ rawN){
  int gw=(blockIdx.x*256+threadIdx.x)>>6;   // 0..2047
  int lane=threadIdx.x&63, half=lane>>5, ch=lane&31;
  int cglob=gw*2+half;
  int p=cglob>>8, c=cglob&255;
  float aP=0.f,aN=0.f;
  for(int q=0;q<16;q++){
    int r=c*16+q;
    size_t ro=(size_t)p*N_+r;
    float ep=eP[ro],en=eN[ro];
    unsigned pr=perm[ro];
    float hv=hp[((size_t)p*N_+pr)*32+ch];
    size_t to=((size_t)p*4097+r)*32+ch;
    TPP[to]=aP; TPN[to]=aN;
    aP+=ep*hv; aN+=en*hv;
  }
  size_t bo=((size_t)p*256+c)*32+ch;
  rawP[bo]=aP; rawN[bo]=aN;
}

// ---------- layer1 relative tables: wave per chunk, width-64 rows ------------
__global__ void __launch_bounds__(256) ktables1(const unsigned* __restrict__ perm,
    const float* __restrict__ eP, const float* __restrict__ eN,
    const float* __restrict__ hp, float* __restrict__ TPP, float* __restrict__ TPN,
    float* __restrict__ rawP, float* __restrict__ rawN){
  int wid=(blockIdx.x*256+threadIdx.x)>>6;   // 0..1023
  int lane=threadIdx.x&63;
  int p=wid>>8, c=wid&255;
  float aP=0.f,aN=0.f;
  for(int q=0;q<16;q++){
    int r=c*16+q;
    size_t ro=(size_t)p*N_+r;
    float ep=eP[ro],en=eN[ro];
    unsigned pr=perm[ro];
    float hv=hp[((size_t)p*N_+pr)*64+lane];
    size_t to=((size_t)p*4097+r)*64+lane;
    TPP[to]=aP; TPN[to]=aN;
    aP+=ep*hv; aN+=en*hv;
  }
  size_t bo=((size_t)p*256+c)*64+lane;
  rawP[bo]=aP; rawN[bo]=aN;
}

// ---------- scan chunk sums -> bases + totals; scalar count prefixes ---------
template<int D>
__global__ void __launch_bounds__(256) kscan(const float* __restrict__ rawP,
    const float* __restrict__ rawN, float* __restrict__ bP, float* __restrict__ bN,
    float* __restrict__ TPP, float* __restrict__ TPN,
    const float* __restrict__ eP, const float* __restrict__ eN,
    float* __restrict__ CPP, float* __restrict__ CPN){
  extern __shared__ float sm[];   // >= max(256*D, 4352)
  int p=blockIdx.x, tid=threadIdx.x;
  for(int pass=0;pass<2;pass++){
    const float* src=pass?rawN:rawP;
    float* dst=pass?bN:bP;
    float* tp=pass?TPN:TPP;
    __syncthreads();
    for(int i=tid;i<256*D;i+=256) sm[i]=src[(size_t)p*256*D+i];
    __syncthreads();
    if(tid<D){
      float r=0.f;
      for(int c=0;c<256;c++){
        dst[((size_t)p*257+c)*D+tid]=r;
        r+=sm[c*D+tid];
      }
      dst[((size_t)p*257+256)*D+tid]=0.f;      // base for lo==4096
      tp[((size_t)p*4097+4096)*D+tid]=r;       // absolute channel totals
    }
  }
  // scalar count prefix passes (folded former kcounts)
  for(int pass=0;pass<2;pass++){
    const float* src=pass?eN:eP;
    float* dst=pass?CPN:CPP;
    __syncthreads();
    for(int i=tid;i<1024;i+=256) ((float4*)sm)[i]=((const float4*)(src+(size_t)p*N_))[i];
    __syncthreads();
    float part=0.f;
    for(int j=0;j<16;j++) part+=sm[tid*16+j];
    sm[4096+tid]=part;
    __syncthreads();
    for(int off=1;off<256;off<<=1){
      float v=(tid>=off)?sm[4096+tid-off]:0.f;
      __syncthreads();
      sm[4096+tid]+=v;
      __syncthreads();
    }
    float a=sm[4096+tid]-part;   // exclusive base
    for(int j=0;j<16;j++){
      dst[(size_t)p*4097+tid*16+j]=a;
      a+=sm[tid*16+j];
    }
    if(tid==255) dst[(size_t)p*4097+4096]=sm[4096+255];
  }
}

// ---------- layer0 row eval + fused layer1 stats accumulation ----------------
__global__ void __launch_bounds__(256) keval0(const float* __restrict__ ss,
                       const float* __restrict__ sv,
                       const float* __restrict__ bP, const float* __restrict__ bN,
                       const float* __restrict__ TPP, const float* __restrict__ TPN,
                       const float* __restrict__ CPP, const float* __restrict__ CPN,
                       const float* __restrict__ bias, float* __restrict__ out,
                       float* __restrict__ stats1){
  int gw=(blockIdx.x*256+threadIdx.x)>>6;   // 0..32767
  int lane=threadIdx.x&63, half=lane>>5, ch=lane&31;
  int row=gw*2+half;
  int p=row>>12, i=row&4095;
  int b=p>>2, h=p&3;
  const float* svp=sv+(size_t)p*N_;
  float ssrc=ss[(size_t)p*N_+i];
  float m=svp[4095];
  float xx=ssrc+m;
  float M=xx>0.f?xx:0.2f*xx;
  float fpos=expf(xx-M),fneg=expf(0.2f*xx-M);
  float th=-ssrc;
  float s1v=svp[ch*128+127];
  unsigned long long bal=__ballot(s1v<=th);
  int c1=half?(int)__popcll(bal>>32):(int)__popcll(bal&0xFFFFFFFFull);
  int lo;
  if(c1>=32){ lo=4096; }
  else{
    float s2v=svp[c1*128+ch*4+3];
    unsigned long long bal2=__ballot(s2v<=th);
    int c2=half?(int)__popcll(bal2>>32):(int)__popcll(bal2&0xFFFFFFFFull);
    int base=c1*128+c2*4;
    float4 qv=*((const float4*)(svp+base));
    int c3=(qv.x<=th)+(qv.y<=th)+(qv.z<=th)+(qv.w<=th);
    lo=base+c3;
  }
  int c=lo>>4;
  float relP=TPP[((size_t)p*4097+lo)*32+ch];
  float relN=TPN[((size_t)p*4097+lo)*32+ch];
  float baP=bP[((size_t)p*257+c)*32+ch];
  float baN=bN[((size_t)p*257+c)*32+ch];
  float tot=TPP[((size_t)p*4097+4096)*32+ch];
  float CPl=CPP[(size_t)p*4097+lo];
  float CNl=CPN[(size_t)p*4097+lo];
  float CT =CPP[(size_t)p*4097+4096];
  float denom=fpos*(CT-CPl)+fneg*CNl;
  float v=fpos*(tot-(baP+relP))+fneg*(baN+relN);
  float r=v/denom+bias[ch];
  r=r>0.f?r:expm1f(r);
  out[((size_t)(b*N_+i))*128+h*32+ch]=r;
  // fused layer-1 instance-norm stats (block covers 8 rows of one p)
  __shared__ float shS[256],shQ[256];
  shS[threadIdx.x]=r; shQ[threadIdx.x]=r*r;
  __syncthreads();
  if(threadIdx.x<32){
    float s=0.f,q=0.f;
    #pragma unroll
    for(int k=0;k<8;k++){s+=shS[threadIdx.x+32*k];q+=shQ[threadIdx.x+32*k];}
    int row0=blockIdx.x*8;
    int p0=row0>>12; int b0=p0>>2,h0=p0&3;
    atomicAdd(&stats1[(size_t)(b0*128+h0*32+threadIdx.x)*2+0],s);
    atomicAdd(&stats1[(size_t)(b0*128+h0*32+threadIdx.x)*2+1],q);
  }
}

// ---------- layer1 row eval: wave per row, width-64 --------------------------
__global__ void __launch_bounds__(256) keval1(const float* __restrict__ ss,
                       const float* __restrict__ sv,
                       const float* __restrict__ bP, const float* __restrict__ bN,
                       const float* __restrict__ TPP, const float* __restrict__ TPN,
                       const float* __restrict__ CPP, const float* __restrict__ CPN,
                       const float* __restrict__ bias, float* __restrict__ out){
  int wid=(blockIdx.x*256+threadIdx.x)>>6;   // p*4096+i
  int lane=threadIdx.x&63;
  int p=wid>>12, i=wid&4095;
  const float* svp=sv+(size_t)p*N_;
  float ssrc=ss[(size_t)p*N_+i];
  float m=svp[4095];
  float xx=ssrc+m;
  float M=xx>0.f?xx:0.2f*xx;
  float fpos=expf(xx-M),fneg=expf(0.2f*xx-M);
  float th=-ssrc;
  float s1v=svp[lane*64+63];
  int c1=(int)__popcll(__ballot(s1v<=th));
  int lo;
  if(c1>=64){ lo=4096; }
  else{
    float s2v=svp[c1*64+lane];
    lo=c1*64+(int)__popcll(__ballot(s2v<=th));
  }
  int c=lo>>4;
  float relP=TPP[((size_t)p*4097+lo)*64+lane];
  float relN=TPN[((size_t)p*4097+lo)*64+lane];
  float baP=bP[((size_t)p*257+c)*64+lane];
  float baN=bN[((size_t)p*257+c)*64+lane];
  float tot=TPP[((size_t)p*4097+4096)*64+lane];
  float CPl=CPP[(size_t)p*4097+lo];
  float CNl=CPN[(size_t)p*4097+lo];
  float CT =CPP[(size_t)p*4097+4096];
  float denom=fpos*(CT-CPl)+fneg*CNl;
  float v=fpos*(tot-(baP+relP))+fneg*(baN+relN);
  out[((size_t)p*N_+i)*64+lane]=v/denom+bias[lane];
}

extern "C" void kernel_launch(void* const* d_in, const int* in_sizes, int n_in,
                              void* d_out, int out_size, void* d_ws, size_t ws_size,
                              hipStream_t stream) {
  const float* x  =(const float*)d_in[0];
  const float* w0 =(const float*)d_in[1];
  const float* as0=(const float*)d_in[2];
  const float* ad0=(const float*)d_in[3];
  const float* b0 =(const float*)d_in[4];
  const float* w1 =(const float*)d_in[5];
  const float* as1=(const float*)d_in[6];
  const float* ad1=(const float*)d_in[7];
  const float* b1 =(const float*)d_in[8];
  float* ws=(float*)d_ws;
  float* out=(float*)d_out;

  float* st0 = ws+OFF_STATS0;
  float* st1 = ws+OFF_STATS1;
  float* hp0 = ws+OFF_HP0;
  float* elu = ws+OFF_ELU;
  float* ss0 = ws+OFF_SS0;  float* sd0 = ws+OFF_SD0;
  unsigned long long* runs0=(unsigned long long*)(ws+OFF_RUNS0);
  float* sv0 = ws+OFF_SV0;
  unsigned* pm0=(unsigned*)(ws+OFF_PM0);
  float* eP0 = ws+OFF_EP0;  float* eN0 = ws+OFF_EN0;
  float* cP0 = ws+OFF_CPP0; float* cN0 = ws+OFF_CPN0;
  float* rP0 = ws+OFF_RAWP0; float* rN0 = ws+OFF_RAWN0;
  float* bP0 = ws+OFF_BP0;  float* bN0 = ws+OFF_BN0;
  float* tP0 = ws+OFF_TPP0; float* tN0 = ws+OFF_TPN0;
  float* hp1 = ws+OFF_HP1;
  float* ss1 = ws+OFF_SS1;  float* sd1 = ws+OFF_SD1;
  unsigned long long* runs1=(unsigned long long*)(ws+OFF_RUNS1);
  float* sv1 = ws+OFF_SV1;
  unsigned* pm1=(unsigned*)(ws+OFF_PM1);
  float* eP1 = ws+OFF_EP1;  float* eN1 = ws+OFF_EN1;
  float* cP1 = ws+OFF_CPP1; float* cN1 = ws+OFF_CPN1;
  float* rP1 = ws+OFF_RAWP1; float* rN1 = ws+OFF_RAWN1;
  float* bP1 = ws+OFF_BP1;  float* bN1 = ws+OFF_BN1;
  float* tP1 = ws+OFF_TPP1; float* tN1 = ws+OFF_TPN1;

  hipMemsetAsync(d_ws, 0, 1536*sizeof(float), stream);

  // ---- layer 0 ----
  kstats<64><<<128,256,0,stream>>>(x,st0);
  kproj0<<<128,256,0,stream>>>(x,st0,w0,as0,ad0,hp0,ss0,sd0);
  ksort_runs<<<64,256,0,stream>>>(sd0,runs0);
  kmerge<<<64,1024,0,stream>>>(runs0,sv0,pm0,eP0,eN0);
  ktables0<<<512,256,0,stream>>>(pm0,eP0,eN0,hp0,tP0,tN0,rP0,rN0);
  kscan<32><<<16,256,256*32*4,stream>>>(rP0,rN0,bP0,bN0,tP0,tN0,eP0,eN0,cP0,cN0);
  keval0<<<8192,256,0,stream>>>(ss0,sv0,bP0,bN0,tP0,tN0,cP0,cN0,b0,elu,st1);
  // ---- layer 1 (stats fused into keval0) ----
  kproj1<<<128,256,0,stream>>>(elu,st1,w1,as1,ad1,hp1,ss1,sd1);
  ksort_runs<<<16,256,0,stream>>>(sd1,runs1);
  kmerge<<<16,1024,0,stream>>>(runs1,sv1,pm1,eP1,eN1);
  ktables1<<<256,256,0,stream>>>(pm1,eP1,eN1,hp1,tP1,tN1,rP1,rN1);
  kscan<64><<<4,256,256*64*4,stream>>>(rP1,rN1,bP1,bN1,tP1,tN1,eP1,eN1,cP1,cN1);
  keval1<<<4096,256,0,stream>>>(ss1,sv1,bP1,bN1,tP1,tN1,cP1,cN1,b1,out);
}

// Round 10
// 282.132 us; speedup vs baseline: 1.1825x; 1.1825x over previous
//
#include <hip/hip_runtime.h>
#include <math.h>

#define N_ 4096

// ---------------- workspace float offsets -----------------------------------
static constexpr size_t OFF_STATS0 = 0;        // [4][64][2]
static constexpr size_t OFF_STATS1 = 512;      // [4][128][2] (memset 1536)
static constexpr size_t OFF_HP0    = 2048;     // [16][4096][32]; ELU aliases
static constexpr size_t OFF_ELU    = 2048;     // [4][4096][128]
static constexpr size_t OFF_SS0    = 2099200;
static constexpr size_t OFF_SD0    = 2164736;
static constexpr size_t OFF_RUNS0  = 2230272;  // u64[16][4096]
static constexpr size_t OFF_SV0    = 2361344;
static constexpr size_t OFF_PM0    = 2426880;
static constexpr size_t OFF_EP0    = 2492416;
static constexpr size_t OFF_EN0    = 2557952;
static constexpr size_t OFF_CPP0   = 2623488;  // [16][4097] scalar count prefixes
static constexpr size_t OFF_CPN0   = 2689040;
static constexpr size_t OFF_RAWP0  = 2754592;  // [16][256][32]
static constexpr size_t OFF_RAWN0  = 2885664;
static constexpr size_t OFF_BP0    = 3016736;  // [16][257][32]
static constexpr size_t OFF_BN0    = 3148320;
static constexpr size_t OFF_TPP0   = 3279904;  // [16][4097][32]
static constexpr size_t OFF_TPN0   = 5377568;  // ends 7475232
// ---- layer1 aliases TPP0/TPN0 region (dead after keval0) ----
static constexpr size_t OFF_HP1    = 3279904;  // [4][4096][64]
static constexpr size_t OFF_SS1    = 4328480;
static constexpr size_t OFF_SD1    = 4344864;
static constexpr size_t OFF_RUNS1  = 4361248;  // u64[4][4096]
static constexpr size_t OFF_SV1    = 4394016;
static constexpr size_t OFF_PM1    = 4410400;
static constexpr size_t OFF_EP1    = 4426784;
static constexpr size_t OFF_EN1    = 4443168;
static constexpr size_t OFF_CPP1   = 4459552;  // [4][4097]
static constexpr size_t OFF_CPN1   = 4475940;
static constexpr size_t OFF_RAWP1  = 4492328;  // [4][256][64]
static constexpr size_t OFF_RAWN1  = 4557864;
static constexpr size_t OFF_BP1    = 4623400;  // [4][257][64]
static constexpr size_t OFF_BN1    = 4689192;
static constexpr size_t OFF_TPP1   = 4754984;  // [4][4097][64]
static constexpr size_t OFF_TPN1   = 5803816;  // end 6852648 floats ~27.4 MB

__device__ __forceinline__ unsigned f2s(float f){
  unsigned u=__float_as_uint(f);
  return u^((u&0x80000000u)?0xFFFFFFFFu:0x80000000u);
}
__device__ __forceinline__ float s2f(unsigned s){
  unsigned u=(s&0x80000000u)?(s^0x80000000u):~s;
  return __uint_as_float(u);
}

// ---------- partial stats for layer0 input (coalesced) -----------------------
template<int C>
__global__ void kstats(const float* __restrict__ x, float* __restrict__ stats){
  int blk=blockIdx.x; int b=blk>>5, seg=blk&31;
  int tid=threadIdx.x;
  const int RPT=256/C;
  const int IT=128/RPT;
  int c=tid%C, rl=tid/C;
  const float* xb=x+(size_t)b*N_*C;
  float s1=0.f,s2=0.f;
  int r0=seg*128+rl;
  for(int i=0;i<IT;i++){
    float v=xb[(size_t)(r0+i*RPT)*C+c];
    s1+=v;s2+=v*v;
  }
  __shared__ float sh1[256],sh2[256];
  sh1[tid]=s1;sh2[tid]=s2;__syncthreads();
  if(tid<C){
    float a1=0.f,a2=0.f;
    for(int g=0;g<RPT;g++){a1+=sh1[g*C+tid];a2+=sh2[g*C+tid];}
    atomicAdd(&stats[(size_t)(b*C+tid)*2+0],a1);
    atomicAdd(&stats[(size_t)(b*C+tid)*2+1],a2);
  }
}

// ---------- layer0 projection; 1 row/thread, h wave-uniform (R8 form) --------
__global__ void __launch_bounds__(256) kproj0(
                       const float* __restrict__ x, const float* __restrict__ stats,
                       const float* __restrict__ w0, const float* __restrict__ asrc,
                       const float* __restrict__ adst, float* __restrict__ hp,
                       float* __restrict__ ss, float* __restrict__ sd){
  __shared__ float4 w4[2048];
  __shared__ float4 av4[64];
  __shared__ float mean[64],rstd[64];
  int tid=threadIdx.x;
  const float4* wg=(const float4*)w0;
  for(int i=tid;i<2048;i+=256) w4[i]=wg[i];
  if(tid<32) av4[tid]=((const float4*)asrc)[tid];
  else if(tid<64) av4[tid]=((const float4*)adst)[tid-32];
  int gid=blockIdx.x*256+tid;
  int b=gid>>14, h=(gid>>12)&3, n=gid&4095;   // wave-uniform h
  if(tid<64){
    float s1=stats[(size_t)(b*64+tid)*2+0],s2=stats[(size_t)(b*64+tid)*2+1];
    float mu=s1*(1.0f/N_);
    float var=s2*(1.0f/N_)-mu*mu;
    mean[tid]=mu; rstd[tid]=rsqrtf(var+1e-5f);
  }
  __syncthreads();
  const float4* hr4=(const float4*)(x+((size_t)(b*N_+n))*64);
  float4 acc[8];
  #pragma unroll
  for(int q=0;q<8;q++) acc[q]=make_float4(0.f,0.f,0.f,0.f);
  #pragma unroll
  for(int ch=0;ch<4;ch++){
    float4 t[4];
    #pragma unroll
    for(int j=0;j<4;j++) t[j]=hr4[ch*4+j];
    #pragma unroll
    for(int j=0;j<4;j++){
      int d0=ch*16+j*4;
      float hv[4];
      hv[0]=(t[j].x-mean[d0+0])*rstd[d0+0];
      hv[1]=(t[j].y-mean[d0+1])*rstd[d0+1];
      hv[2]=(t[j].z-mean[d0+2])*rstd[d0+2];
      hv[3]=(t[j].w-mean[d0+3])*rstd[d0+3];
      #pragma unroll
      for(int dd=0;dd<4;dd++){
        float hvv=hv[dd];
        #pragma unroll
        for(int q=0;q<8;q++){
          float4 wv=w4[(h*64+d0+dd)*8+q];
          acc[q].x+=hvv*wv.x;acc[q].y+=hvv*wv.y;acc[q].z+=hvv*wv.z;acc[q].w+=hvv*wv.w;
        }
      }
    }
  }
  float ssv=0.f,sdv=0.f;
  #pragma unroll
  for(int q=0;q<8;q++){
    float4 a1=av4[h*8+q],a2=av4[32+h*8+q];
    ssv+=acc[q].x*a1.x+acc[q].y*a1.y+acc[q].z*a1.z+acc[q].w*a1.w;
    sdv+=acc[q].x*a2.x+acc[q].y*a2.y+acc[q].z*a2.z+acc[q].w*a2.w;
  }
  int p=b*4+h;
  float4* o4=(float4*)(hp+((size_t)p*N_+n)*32);
  #pragma unroll
  for(int q=0;q<8;q++) o4[q]=acc[q];
  ss[(size_t)p*N_+n]=ssv; sd[(size_t)p*N_+n]=sdv;
}

// ---------- layer1 projection; 1 row/thread, q4 wave-uniform (R8 form) -------
__global__ void __launch_bounds__(256) kproj1(
                       const float* __restrict__ x, const float* __restrict__ stats,
                       const float* __restrict__ w1, const float* __restrict__ asrc,
                       const float* __restrict__ adst, float* __restrict__ hp,
                       float* __restrict__ ss, float* __restrict__ sd){
  __shared__ float4 w4[2048];
  __shared__ float wa[128],wd[128],mean[128],rstd[128];
  int tid=threadIdx.x;
  const float4* wg=(const float4*)w1;
  for(int i=tid;i<2048;i+=256) w4[i]=wg[i];
  int gid=blockIdx.x*256+tid;
  int b=gid>>14, q4=(gid>>12)&3, n=gid&4095;  // wave-uniform q4
  if(tid<128){
    float s1a=0.f,s2a=0.f;
    for(int k=0;k<64;k++){float wv=w1[tid*64+k];s1a+=wv*asrc[k];s2a+=wv*adst[k];}
    wa[tid]=s1a;wd[tid]=s2a;
    float s1=stats[(size_t)(b*128+tid)*2+0],s2=stats[(size_t)(b*128+tid)*2+1];
    float mu=s1*(1.0f/N_);
    float var=s2*(1.0f/N_)-mu*mu;
    mean[tid]=mu; rstd[tid]=rsqrtf(var+1e-5f);
  }
  __syncthreads();
  const float4* hr4=(const float4*)(x+((size_t)(b*N_+n))*128);
  float4 acc[4];
  #pragma unroll
  for(int q=0;q<4;q++) acc[q]=make_float4(0.f,0.f,0.f,0.f);
  float s1=0.f,s2=0.f;
  #pragma unroll
  for(int ch=0;ch<8;ch++){
    float4 t[4];
    #pragma unroll
    for(int j=0;j<4;j++) t[j]=hr4[ch*4+j];
    #pragma unroll
    for(int j=0;j<4;j++){
      int d0=ch*16+j*4;
      float hv[4];
      hv[0]=(t[j].x-mean[d0+0])*rstd[d0+0];
      hv[1]=(t[j].y-mean[d0+1])*rstd[d0+1];
      hv[2]=(t[j].z-mean[d0+2])*rstd[d0+2];
      hv[3]=(t[j].w-mean[d0+3])*rstd[d0+3];
      #pragma unroll
      for(int dd=0;dd<4;dd++){
        float hvv=hv[dd]; int d=d0+dd;
        s1+=hvv*wa[d]; s2+=hvv*wd[d];
        #pragma unroll
        for(int q=0;q<4;q++){
          float4 wv=w4[d*16+q4*4+q];
          acc[q].x+=hvv*wv.x;acc[q].y+=hvv*wv.y;acc[q].z+=hvv*wv.z;acc[q].w+=hvv*wv.w;
        }
      }
    }
  }
  float4* o4=(float4*)(hp+((size_t)(b*N_+n))*64+q4*16);
  #pragma unroll
  for(int q=0;q<4;q++) o4[q]=acc[q];
  if(q4==0){
    ss[(size_t)b*N_+n]=s1;sd[(size_t)b*N_+n]=s2;
  }
}

// ---------- sort runs of 1024 (packed u64 = key<<32 | orig_idx) --------------
__global__ void __launch_bounds__(256) ksort_runs(const float* __restrict__ sdst,
                                                  unsigned long long* __restrict__ runs){
  __shared__ unsigned long long sm[1024];
  int p=blockIdx.x>>2, run=blockIdx.x&3;
  int tid=threadIdx.x;
  const float* s=sdst+(size_t)p*N_+run*1024;
  for(int l=tid;l<1024;l+=256){
    unsigned key=f2s(s[l]);
    sm[l]=((unsigned long long)key<<32)|(unsigned)(run*1024+l);
  }
  for(unsigned k=2;k<=1024u;k<<=1)
    for(unsigned j=k>>1;j>0;j>>=1){
      __syncthreads();
      for(unsigned t=tid;t<512u;t+=256u){
        unsigned i=((t&~(j-1))<<1)|(t&(j-1));
        unsigned q=i|j;
        bool up=((i&k)==0);
        unsigned long long a=sm[i],b=sm[q];
        if((a>b)==up){sm[i]=b;sm[q]=a;}
      }
    }
  __syncthreads();
  unsigned long long* rg=runs+(size_t)p*N_+run*1024;
  for(int l=tid;l<1024;l+=256) rg[l]=sm[l];
}

// ---------- merge 4 sorted runs by rank (binary search in LDS) ---------------
__global__ void __launch_bounds__(1024) kmerge(const unsigned long long* __restrict__ runs,
    float* __restrict__ sv, unsigned* __restrict__ perm,
    float* __restrict__ eP, float* __restrict__ eN){
  __shared__ unsigned long long sm[4096];
  int p=blockIdx.x>>2, cg=blockIdx.x&3;
  int tid=threadIdx.x;
  const unsigned long long* rg=runs+(size_t)p*N_;
  for(int l=tid;l<4096;l+=1024) sm[l]=rg[l];
  __syncthreads();
  unsigned long long e=sm[cg*1024+tid];
  int rank=tid;
  #pragma unroll
  for(int o=0;o<4;o++){
    if(o==cg) continue;
    const unsigned long long* base=sm+o*1024;
    int lo=0,hi=1024;
    while(lo<hi){int mid=(lo+hi)>>1; if(base[mid]<e) lo=mid+1; else hi=mid;}
    rank+=lo;
  }
  unsigned long long mk=sm[1023];
  if(sm[2047]>mk) mk=sm[2047];
  if(sm[3071]>mk) mk=sm[3071];
  if(sm[4095]>mk) mk=sm[4095];
  float m=s2f((unsigned)(mk>>32));
  float v=s2f((unsigned)(e>>32));
  size_t o=(size_t)p*N_+rank;
  sv[o]=v;
  perm[o]=(unsigned)(e&0xffffffffu);
  eP[o]=expf(v-m);
  eN[o]=expf(0.2f*(v-m));
}

// ---------- layer0 relative tables: 2 chunks per wave, width-32 rows ---------
__global__ void __launch_bounds__(256) ktables0(const unsigned* __restrict__ perm,
    const float* __restrict__ eP, const float* __restrict__ eN,
    const float* __restrict__ hp, float* __restrict__ TPP, float* __restrict__ TPN,
    float* __restrict__ rawP, float* __restrict__ rawN){
  int gw=(blockIdx.x*256+threadIdx.x)>>6;   // 0..2047
  int lane=threadIdx.x&63, half=lane>>5, ch=lane&31;
  int cglob=gw*2+half;
  int p=cglob>>8, c=cglob&255;
  float aP=0.f,aN=0.f;
  for(int q=0;q<16;q++){
    int r=c*16+q;
    size_t ro=(size_t)p*N_+r;
    float ep=eP[ro],en=eN[ro];
    unsigned pr=perm[ro];
    float hv=hp[((size_t)p*N_+pr)*32+ch];
    size_t to=((size_t)p*4097+r)*32+ch;
    TPP[to]=aP; TPN[to]=aN;
    aP+=ep*hv; aN+=en*hv;
  }
  size_t bo=((size_t)p*256+c)*32+ch;
  rawP[bo]=aP; rawN[bo]=aN;
}

// ---------- layer1 relative tables: wave per chunk, width-64 rows ------------
__global__ void __launch_bounds__(256) ktables1(const unsigned* __restrict__ perm,
    const float* __restrict__ eP, const float* __restrict__ eN,
    const float* __restrict__ hp, float* __restrict__ TPP, float* __restrict__ TPN,
    float* __restrict__ rawP, float* __restrict__ rawN){
  int wid=(blockIdx.x*256+threadIdx.x)>>6;   // 0..1023
  int lane=threadIdx.x&63;
  int p=wid>>8, c=wid&255;
  float aP=0.f,aN=0.f;
  for(int q=0;q<16;q++){
    int r=c*16+q;
    size_t ro=(size_t)p*N_+r;
    float ep=eP[ro],en=eN[ro];
    unsigned pr=perm[ro];
    float hv=hp[((size_t)p*N_+pr)*64+lane];
    size_t to=((size_t)p*4097+r)*64+lane;
    TPP[to]=aP; TPN[to]=aN;
    aP+=ep*hv; aN+=en*hv;
  }
  size_t bo=((size_t)p*256+c)*64+lane;
  rawP[bo]=aP; rawN[bo]=aN;
}

// ---------- scan chunk sums -> bases + totals; scalar count prefixes ---------
template<int D>
__global__ void __launch_bounds__(256) kscan(const float* __restrict__ rawP,
    const float* __restrict__ rawN, float* __restrict__ bP, float* __restrict__ bN,
    float* __restrict__ TPP, float* __restrict__ TPN,
    const float* __restrict__ eP, const float* __restrict__ eN,
    float* __restrict__ CPP, float* __restrict__ CPN){
  extern __shared__ float sm[];   // >= max(256*D, 4352)
  int p=blockIdx.x, tid=threadIdx.x;
  for(int pass=0;pass<2;pass++){
    const float* src=pass?rawN:rawP;
    float* dst=pass?bN:bP;
    float* tp=pass?TPN:TPP;
    __syncthreads();
    for(int i=tid;i<256*D;i+=256) sm[i]=src[(size_t)p*256*D+i];
    __syncthreads();
    if(tid<D){
      float r=0.f;
      for(int c=0;c<256;c++){
        dst[((size_t)p*257+c)*D+tid]=r;
        r+=sm[c*D+tid];
      }
      dst[((size_t)p*257+256)*D+tid]=0.f;      // base for lo==4096
      tp[((size_t)p*4097+4096)*D+tid]=r;       // absolute channel totals
    }
  }
  // scalar count prefix passes (folded former kcounts)
  for(int pass=0;pass<2;pass++){
    const float* src=pass?eN:eP;
    float* dst=pass?CPN:CPP;
    __syncthreads();
    for(int i=tid;i<1024;i+=256) ((float4*)sm)[i]=((const float4*)(src+(size_t)p*N_))[i];
    __syncthreads();
    float part=0.f;
    for(int j=0;j<16;j++) part+=sm[tid*16+j];
    sm[4096+tid]=part;
    __syncthreads();
    for(int off=1;off<256;off<<=1){
      float v=(tid>=off)?sm[4096+tid-off]:0.f;
      __syncthreads();
      sm[4096+tid]+=v;
      __syncthreads();
    }
    float a=sm[4096+tid]-part;   // exclusive base
    for(int j=0;j<16;j++){
      dst[(size_t)p*4097+tid*16+j]=a;
      a+=sm[tid*16+j];
    }
    if(tid==255) dst[(size_t)p*4097+4096]=sm[4096+255];
  }
}

// ---------- layer0 row eval + fused layer1 stats accumulation ----------------
__global__ void __launch_bounds__(256) keval0(const float* __restrict__ ss,
                       const float* __restrict__ sv,
                       const float* __restrict__ bP, const float* __restrict__ bN,
                       const float* __restrict__ TPP, const float* __restrict__ TPN,
                       const float* __restrict__ CPP, const float* __restrict__ CPN,
                       const float* __restrict__ bias, float* __restrict__ out,
                       float* __restrict__ stats1){
  int gw=(blockIdx.x*256+threadIdx.x)>>6;   // 0..32767
  int lane=threadIdx.x&63, half=lane>>5, ch=lane&31;
  int row=gw*2+half;
  int p=row>>12, i=row&4095;
  int b=p>>2, h=p&3;
  const float* svp=sv+(size_t)p*N_;
  float ssrc=ss[(size_t)p*N_+i];
  float m=svp[4095];
  float xx=ssrc+m;
  float M=xx>0.f?xx:0.2f*xx;
  float fpos=expf(xx-M),fneg=expf(0.2f*xx-M);
  float th=-ssrc;
  float s1v=svp[ch*128+127];
  unsigned long long bal=__ballot(s1v<=th);
  int c1=half?(int)__popcll(bal>>32):(int)__popcll(bal&0xFFFFFFFFull);
  int lo;
  if(c1>=32){ lo=4096; }
  else{
    float s2v=svp[c1*128+ch*4+3];
    unsigned long long bal2=__ballot(s2v<=th);
    int c2=half?(int)__popcll(bal2>>32):(int)__popcll(bal2&0xFFFFFFFFull);
    int base=c1*128+c2*4;
    float4 qv=*((const float4*)(svp+base));
    int c3=(qv.x<=th)+(qv.y<=th)+(qv.z<=th)+(qv.w<=th);
    lo=base+c3;
  }
  int c=lo>>4;
  float relP=TPP[((size_t)p*4097+lo)*32+ch];
  float relN=TPN[((size_t)p*4097+lo)*32+ch];
  float baP=bP[((size_t)p*257+c)*32+ch];
  float baN=bN[((size_t)p*257+c)*32+ch];
  float tot=TPP[((size_t)p*4097+4096)*32+ch];
  float CPl=CPP[(size_t)p*4097+lo];
  float CNl=CPN[(size_t)p*4097+lo];
  float CT =CPP[(size_t)p*4097+4096];
  float denom=fpos*(CT-CPl)+fneg*CNl;
  float v=fpos*(tot-(baP+relP))+fneg*(baN+relN);
  float r=v/denom+bias[ch];
  r=r>0.f?r:expm1f(r);
  out[((size_t)(b*N_+i))*128+h*32+ch]=r;
  // fused layer-1 instance-norm stats (block covers 8 rows of one p)
  __shared__ float shS[256],shQ[256];
  shS[threadIdx.x]=r; shQ[threadIdx.x]=r*r;
  __syncthreads();
  if(threadIdx.x<32){
    float s=0.f,q=0.f;
    #pragma unroll
    for(int k=0;k<8;k++){s+=shS[threadIdx.x+32*k];q+=shQ[threadIdx.x+32*k];}
    int row0=blockIdx.x*8;
    int p0=row0>>12; int b0=p0>>2,h0=p0&3;
    atomicAdd(&stats1[(size_t)(b0*128+h0*32+threadIdx.x)*2+0],s);
    atomicAdd(&stats1[(size_t)(b0*128+h0*32+threadIdx.x)*2+1],q);
  }
}

// ---------- layer1 row eval: wave per row, width-64 --------------------------
__global__ void __launch_bounds__(256) keval1(const float* __restrict__ ss,
                       const float* __restrict__ sv,
                       const float* __restrict__ bP, const float* __restrict__ bN,
                       const float* __restrict__ TPP, const float* __restrict__ TPN,
                       const float* __restrict__ CPP, const float* __restrict__ CPN,
                       const float* __restrict__ bias, float* __restrict__ out){
  int wid=(blockIdx.x*256+threadIdx.x)>>6;   // p*4096+i
  int lane=threadIdx.x&63;
  int p=wid>>12, i=wid&4095;
  const float* svp=sv+(size_t)p*N_;
  float ssrc=ss[(size_t)p*N_+i];
  float m=svp[4095];
  float xx=ssrc+m;
  float M=xx>0.f?xx:0.2f*xx;
  float fpos=expf(xx-M),fneg=expf(0.2f*xx-M);
  float th=-ssrc;
  float s1v=svp[lane*64+63];
  int c1=(int)__popcll(__ballot(s1v<=th));
  int lo;
  if(c1>=64){ lo=4096; }
  else{
    float s2v=svp[c1*64+lane];
    lo=c1*64+(int)__popcll(__ballot(s2v<=th));
  }
  int c=lo>>4;
  float relP=TPP[((size_t)p*4097+lo)*64+lane];
  float relN=TPN[((size_t)p*4097+lo)*64+lane];
  float baP=bP[((size_t)p*257+c)*64+lane];
  float baN=bN[((size_t)p*257+c)*64+lane];
  float tot=TPP[((size_t)p*4097+4096)*64+lane];
  float CPl=CPP[(size_t)p*4097+lo];
  float CNl=CPN[(size_t)p*4097+lo];
  float CT =CPP[(size_t)p*4097+4096];
  float denom=fpos*(CT-CPl)+fneg*CNl;
  float v=fpos*(tot-(baP+relP))+fneg*(baN+relN);
  out[((size_t)p*N_+i)*64+lane]=v/denom+bias[lane];
}

extern "C" void kernel_launch(void* const* d_in, const int* in_sizes, int n_in,
                              void* d_out, int out_size, void* d_ws, size_t ws_size,
                              hipStream_t stream) {
  const float* x  =(const float*)d_in[0];
  const float* w0 =(const float*)d_in[1];
  const float* as0=(const float*)d_in[2];
  const float* ad0=(const float*)d_in[3];
  const float* b0 =(const float*)d_in[4];
  const float* w1 =(const float*)d_in[5];
  const float* as1=(const float*)d_in[6];
  const float* ad1=(const float*)d_in[7];
  const float* b1 =(const float*)d_in[8];
  float* ws=(float*)d_ws;
  float* out=(float*)d_out;

  float* st0 = ws+OFF_STATS0;
  float* st1 = ws+OFF_STATS1;
  float* hp0 = ws+OFF_HP0;
  float* elu = ws+OFF_ELU;
  float* ss0 = ws+OFF_SS0;  float* sd0 = ws+OFF_SD0;
  unsigned long long* runs0=(unsigned long long*)(ws+OFF_RUNS0);
  float* sv0 = ws+OFF_SV0;
  unsigned* pm0=(unsigned*)(ws+OFF_PM0);
  float* eP0 = ws+OFF_EP0;  float* eN0 = ws+OFF_EN0;
  float* cP0 = ws+OFF_CPP0; float* cN0 = ws+OFF_CPN0;
  float* rP0 = ws+OFF_RAWP0; float* rN0 = ws+OFF_RAWN0;
  float* bP0 = ws+OFF_BP0;  float* bN0 = ws+OFF_BN0;
  float* tP0 = ws+OFF_TPP0; float* tN0 = ws+OFF_TPN0;
  float* hp1 = ws+OFF_HP1;
  float* ss1 = ws+OFF_SS1;  float* sd1 = ws+OFF_SD1;
  unsigned long long* runs1=(unsigned long long*)(ws+OFF_RUNS1);
  float* sv1 = ws+OFF_SV1;
  unsigned* pm1=(unsigned*)(ws+OFF_PM1);
  float* eP1 = ws+OFF_EP1;  float* eN1 = ws+OFF_EN1;
  float* cP1 = ws+OFF_CPP1; float* cN1 = ws+OFF_CPN1;
  float* rP1 = ws+OFF_RAWP1; float* rN1 = ws+OFF_RAWN1;
  float* bP1 = ws+OFF_BP1;  float* bN1 = ws+OFF_BN1;
  float* tP1 = ws+OFF_TPP1; float* tN1 = ws+OFF_TPN1;

  hipMemsetAsync(d_ws, 0, 1536*sizeof(float), stream);

  // ---- layer 0 ----
  kstats<64><<<128,256,0,stream>>>(x,st0);
  kproj0<<<256,256,0,stream>>>(x,st0,w0,as0,ad0,hp0,ss0,sd0);
  ksort_runs<<<64,256,0,stream>>>(sd0,runs0);
  kmerge<<<64,1024,0,stream>>>(runs0,sv0,pm0,eP0,eN0);
  ktables0<<<512,256,0,stream>>>(pm0,eP0,eN0,hp0,tP0,tN0,rP0,rN0);
  kscan<32><<<16,256,256*32*4,stream>>>(rP0,rN0,bP0,bN0,tP0,tN0,eP0,eN0,cP0,cN0);
  keval0<<<8192,256,0,stream>>>(ss0,sv0,bP0,bN0,tP0,tN0,cP0,cN0,b0,elu,st1);
  // ---- layer 1 (stats fused into keval0) ----
  kproj1<<<256,256,0,stream>>>(elu,st1,w1,as1,ad1,hp1,ss1,sd1);
  ksort_runs<<<16,256,0,stream>>>(sd1,runs1);
  kmerge<<<16,1024,0,stream>>>(runs1,sv1,pm1,eP1,eN1);
  ktables1<<<256,256,0,stream>>>(pm1,eP1,eN1,hp1,tP1,tN1,rP1,rN1);
  kscan<64><<<4,256,256*64*4,stream>>>(rP1,rN1,bP1,bN1,tP1,tN1,eP1,eN1,cP1,cN1);
  keval1<<<4096,256,0,stream>>>(ss1,sv1,bP1,bN1,tP1,tN1,cP1,cN1,b1,out);
}

// Round 11
// 233.428 us; speedup vs baseline: 1.4292x; 1.2086x over previous
//
#include <hip/hip_runtime.h>
#include <math.h>

#define N_ 4096

// ---------------- workspace float offsets -----------------------------------
static constexpr size_t OFF_STATS0 = 0;        // [4][64][2]
static constexpr size_t OFF_STATS1 = 512;      // [4][128][2] (memset 1536)
static constexpr size_t OFF_HP0    = 2048;     // [16][4096][32]; ELU aliases
static constexpr size_t OFF_ELU    = 2048;     // [4][4096][128]
static constexpr size_t OFF_SS0    = 2099200;
static constexpr size_t OFF_SD0    = 2164736;
static constexpr size_t OFF_RUNS0  = 2230272;  // u64[16][4096]
static constexpr size_t OFF_SV0    = 2361344;
static constexpr size_t OFF_PM0    = 2426880;
static constexpr size_t OFF_EP0    = 2492416;
static constexpr size_t OFF_EN0    = 2557952;
static constexpr size_t OFF_CPP0   = 2623488;  // [16][4097] scalar count prefixes
static constexpr size_t OFF_CPN0   = 2689040;
static constexpr size_t OFF_RAWP0  = 2754592;  // [16][256][32]
static constexpr size_t OFF_RAWN0  = 2885664;
static constexpr size_t OFF_BP0    = 3016736;  // [16][257][32]
static constexpr size_t OFF_BN0    = 3148320;
static constexpr size_t OFF_TPP0   = 3279904;  // [16][4097][32]
static constexpr size_t OFF_TPN0   = 5377568;  // ends 7475232
// ---- layer1 aliases TPP0/TPN0 region (dead after keval0) ----
static constexpr size_t OFF_HP1    = 3279904;  // [4][4096][64]
static constexpr size_t OFF_SS1    = 4328480;
static constexpr size_t OFF_SD1    = 4344864;
static constexpr size_t OFF_RUNS1  = 4361248;  // u64[4][4096]
static constexpr size_t OFF_SV1    = 4394016;
static constexpr size_t OFF_PM1    = 4410400;
static constexpr size_t OFF_EP1    = 4426784;
static constexpr size_t OFF_EN1    = 4443168;
static constexpr size_t OFF_CPP1   = 4459552;  // [4][4097]
static constexpr size_t OFF_CPN1   = 4475940;
static constexpr size_t OFF_RAWP1  = 4492328;  // [4][256][64]
static constexpr size_t OFF_RAWN1  = 4557864;
static constexpr size_t OFF_BP1    = 4623400;  // [4][257][64]
static constexpr size_t OFF_BN1    = 4689192;
static constexpr size_t OFF_TPP1   = 4754984;  // [4][4097][64]
static constexpr size_t OFF_TPN1   = 5803816;  // end 6852648 floats ~27.4 MB

__device__ __forceinline__ unsigned f2s(float f){
  unsigned u=__float_as_uint(f);
  return u^((u&0x80000000u)?0xFFFFFFFFu:0x80000000u);
}
__device__ __forceinline__ float s2f(unsigned s){
  unsigned u=(s&0x80000000u)?(s^0x80000000u):~s;
  return __uint_as_float(u);
}

// ---------- partial stats (coalesced) + atomic accumulate --------------------
template<int C>
__global__ void kstats(const float* __restrict__ x, float* __restrict__ stats){
  int blk=blockIdx.x; int b=blk>>5, seg=blk&31;
  int tid=threadIdx.x;
  const int RPT=256/C;
  const int IT=128/RPT;
  int c=tid%C, rl=tid/C;
  const float* xb=x+(size_t)b*N_*C;
  float s1=0.f,s2=0.f;
  int r0=seg*128+rl;
  for(int i=0;i<IT;i++){
    float v=xb[(size_t)(r0+i*RPT)*C+c];
    s1+=v;s2+=v*v;
  }
  __shared__ float sh1[256],sh2[256];
  sh1[tid]=s1;sh2[tid]=s2;__syncthreads();
  if(tid<C){
    float a1=0.f,a2=0.f;
    for(int g=0;g<RPT;g++){a1+=sh1[g*C+tid];a2+=sh2[g*C+tid];}
    atomicAdd(&stats[(size_t)(b*C+tid)*2+0],a1);
    atomicAdd(&stats[(size_t)(b*C+tid)*2+1],a2);
  }
}

// ---------- layer0 projection; h wave-uniform -> LDS broadcast (no conflict) -
__global__ void __launch_bounds__(256) kproj0(
                       const float* __restrict__ x, const float* __restrict__ stats,
                       const float* __restrict__ w0, const float* __restrict__ asrc,
                       const float* __restrict__ adst, float* __restrict__ hp,
                       float* __restrict__ ss, float* __restrict__ sd){
  __shared__ float4 w4[2048];
  __shared__ float4 av4[64];
  __shared__ float mean[64],rstd[64];
  int tid=threadIdx.x;
  const float4* wg=(const float4*)w0;
  for(int i=tid;i<2048;i+=256) w4[i]=wg[i];
  if(tid<32) av4[tid]=((const float4*)asrc)[tid];
  else if(tid<64) av4[tid]=((const float4*)adst)[tid-32];
  int gid=blockIdx.x*256+tid;
  int b=gid>>14, h=(gid>>12)&3, n=gid&4095;   // wave-uniform h
  if(tid<64){
    float s1=stats[(size_t)(b*64+tid)*2+0],s2=stats[(size_t)(b*64+tid)*2+1];
    float mu=s1*(1.0f/N_);
    float var=s2*(1.0f/N_)-mu*mu;
    mean[tid]=mu; rstd[tid]=rsqrtf(var+1e-5f);
  }
  __syncthreads();
  const float4* hr4=(const float4*)(x+((size_t)(b*N_+n))*64);
  float4 acc[8];
  #pragma unroll
  for(int q=0;q<8;q++) acc[q]=make_float4(0.f,0.f,0.f,0.f);
  #pragma unroll
  for(int ch=0;ch<4;ch++){
    float4 t[4];
    #pragma unroll
    for(int j=0;j<4;j++) t[j]=hr4[ch*4+j];
    #pragma unroll
    for(int j=0;j<4;j++){
      int d0=ch*16+j*4;
      float hv[4];
      hv[0]=(t[j].x-mean[d0+0])*rstd[d0+0];
      hv[1]=(t[j].y-mean[d0+1])*rstd[d0+1];
      hv[2]=(t[j].z-mean[d0+2])*rstd[d0+2];
      hv[3]=(t[j].w-mean[d0+3])*rstd[d0+3];
      #pragma unroll
      for(int dd=0;dd<4;dd++){
        float hvv=hv[dd];
        #pragma unroll
        for(int q=0;q<8;q++){
          float4 wv=w4[(h*64+d0+dd)*8+q];
          acc[q].x+=hvv*wv.x;acc[q].y+=hvv*wv.y;acc[q].z+=hvv*wv.z;acc[q].w+=hvv*wv.w;
        }
      }
    }
  }
  float ssv=0.f,sdv=0.f;
  #pragma unroll
  for(int q=0;q<8;q++){
    float4 a1=av4[h*8+q],a2=av4[32+h*8+q];
    ssv+=acc[q].x*a1.x+acc[q].y*a1.y+acc[q].z*a1.z+acc[q].w*a1.w;
    sdv+=acc[q].x*a2.x+acc[q].y*a2.y+acc[q].z*a2.z+acc[q].w*a2.w;
  }
  int p=b*4+h;
  float4* o4=(float4*)(hp+((size_t)p*N_+n)*32);
  #pragma unroll
  for(int q=0;q<8;q++) o4[q]=acc[q];
  ss[(size_t)p*N_+n]=ssv; sd[(size_t)p*N_+n]=sdv;
}

// ---------- layer1 projection; q4 wave-uniform -> LDS broadcast --------------
__global__ void __launch_bounds__(256) kproj1(
                       const float* __restrict__ x, const float* __restrict__ stats,
                       const float* __restrict__ w1, const float* __restrict__ asrc,
                       const float* __restrict__ adst, float* __restrict__ hp,
                       float* __restrict__ ss, float* __restrict__ sd){
  __shared__ float4 w4[2048];
  __shared__ float wa[128],wd[128],mean[128],rstd[128];
  int tid=threadIdx.x;
  const float4* wg=(const float4*)w1;
  for(int i=tid;i<2048;i+=256) w4[i]=wg[i];
  int gid=blockIdx.x*256+tid;
  int b=gid>>14, q4=(gid>>12)&3, n=gid&4095;  // wave-uniform q4
  if(tid<128){
    float s1a=0.f,s2a=0.f;
    for(int k=0;k<64;k++){float wv=w1[tid*64+k];s1a+=wv*asrc[k];s2a+=wv*adst[k];}
    wa[tid]=s1a;wd[tid]=s2a;
    float s1=stats[(size_t)(b*128+tid)*2+0],s2=stats[(size_t)(b*128+tid)*2+1];
    float mu=s1*(1.0f/N_);
    float var=s2*(1.0f/N_)-mu*mu;
    mean[tid]=mu; rstd[tid]=rsqrtf(var+1e-5f);
  }
  __syncthreads();
  const float4* hr4=(const float4*)(x+((size_t)(b*N_+n))*128);
  float4 acc[4];
  #pragma unroll
  for(int q=0;q<4;q++) acc[q]=make_float4(0.f,0.f,0.f,0.f);
  float s1=0.f,s2=0.f;
  #pragma unroll
  for(int ch=0;ch<8;ch++){
    float4 t[4];
    #pragma unroll
    for(int j=0;j<4;j++) t[j]=hr4[ch*4+j];
    #pragma unroll
    for(int j=0;j<4;j++){
      int d0=ch*16+j*4;
      float hv[4];
      hv[0]=(t[j].x-mean[d0+0])*rstd[d0+0];
      hv[1]=(t[j].y-mean[d0+1])*rstd[d0+1];
      hv[2]=(t[j].z-mean[d0+2])*rstd[d0+2];
      hv[3]=(t[j].w-mean[d0+3])*rstd[d0+3];
      #pragma unroll
      for(int dd=0;dd<4;dd++){
        float hvv=hv[dd]; int d=d0+dd;
        s1+=hvv*wa[d]; s2+=hvv*wd[d];
        #pragma unroll
        for(int q=0;q<4;q++){
          float4 wv=w4[d*16+q4*4+q];
          acc[q].x+=hvv*wv.x;acc[q].y+=hvv*wv.y;acc[q].z+=hvv*wv.z;acc[q].w+=hvv*wv.w;
        }
      }
    }
  }
  float4* o4=(float4*)(hp+((size_t)(b*N_+n))*64+q4*16);
  #pragma unroll
  for(int q=0;q<4;q++) o4[q]=acc[q];
  if(q4==0){
    ss[(size_t)b*N_+n]=s1;sd[(size_t)b*N_+n]=s2;
  }
}

// ---------- sort runs of 1024 (packed u64 = key<<32 | orig_idx) --------------
__global__ void __launch_bounds__(256) ksort_runs(const float* __restrict__ sdst,
                                                  unsigned long long* __restrict__ runs){
  __shared__ unsigned long long sm[1024];
  int p=blockIdx.x>>2, run=blockIdx.x&3;
  int tid=threadIdx.x;
  const float* s=sdst+(size_t)p*N_+run*1024;
  for(int l=tid;l<1024;l+=256){
    unsigned key=f2s(s[l]);
    sm[l]=((unsigned long long)key<<32)|(unsigned)(run*1024+l);
  }
  for(unsigned k=2;k<=1024u;k<<=1)
    for(unsigned j=k>>1;j>0;j>>=1){
      __syncthreads();
      for(unsigned t=tid;t<512u;t+=256u){
        unsigned i=((t&~(j-1))<<1)|(t&(j-1));
        unsigned q=i|j;
        bool up=((i&k)==0);
        unsigned long long a=sm[i],b=sm[q];
        if((a>b)==up){sm[i]=b;sm[q]=a;}
      }
    }
  __syncthreads();
  unsigned long long* rg=runs+(size_t)p*N_+run*1024;
  for(int l=tid;l<1024;l+=256) rg[l]=sm[l];
}

// ---------- merge 4 sorted runs by rank (binary search in LDS) ---------------
__global__ void __launch_bounds__(1024) kmerge(const unsigned long long* __restrict__ runs,
    float* __restrict__ sv, unsigned* __restrict__ perm,
    float* __restrict__ eP, float* __restrict__ eN){
  __shared__ unsigned long long sm[4096];
  int p=blockIdx.x>>2, cg=blockIdx.x&3;
  int tid=threadIdx.x;
  const unsigned long long* rg=runs+(size_t)p*N_;
  for(int l=tid;l<4096;l+=1024) sm[l]=rg[l];
  __syncthreads();
  unsigned long long e=sm[cg*1024+tid];
  int rank=tid;
  #pragma unroll
  for(int o=0;o<4;o++){
    if(o==cg) continue;
    const unsigned long long* base=sm+o*1024;
    int lo=0,hi=1024;
    while(lo<hi){int mid=(lo+hi)>>1; if(base[mid]<e) lo=mid+1; else hi=mid;}
    rank+=lo;
  }
  unsigned long long mk=sm[1023];
  if(sm[2047]>mk) mk=sm[2047];
  if(sm[3071]>mk) mk=sm[3071];
  if(sm[4095]>mk) mk=sm[4095];
  float m=s2f((unsigned)(mk>>32));
  float v=s2f((unsigned)(e>>32));
  size_t o=(size_t)p*N_+rank;
  sv[o]=v;
  perm[o]=(unsigned)(e&0xffffffffu);
  eP[o]=expf(v-m);
  eN[o]=expf(0.2f*(v-m));
}

// ---------- absolute scalar count prefixes per p (block scan) ----------------
__global__ void __launch_bounds__(1024) kcounts(const float* __restrict__ eP,
    const float* __restrict__ eN, float* __restrict__ CPP, float* __restrict__ CPN){
  __shared__ float sp[1024],sn[1024];
  int p=blockIdx.x, t=threadIdx.x;
  float4 e4=((const float4*)(eP+(size_t)p*N_))[t];
  float4 n4=((const float4*)(eN+(size_t)p*N_))[t];
  float lp=e4.x+e4.y+e4.z+e4.w;
  float ln=n4.x+n4.y+n4.z+n4.w;
  sp[t]=lp; sn[t]=ln; __syncthreads();
  for(int off=1;off<1024;off<<=1){
    float vp=(t>=off)?sp[t-off]:0.f;
    float vn=(t>=off)?sn[t-off]:0.f;
    __syncthreads();
    sp[t]+=vp; sn[t]+=vn;
    __syncthreads();
  }
  float bp=sp[t]-lp, bn=sn[t]-ln;   // exclusive base for this thread's 4
  size_t o=(size_t)p*4097+t*4;
  float a=bp;          CPP[o+0]=a;
  a+=e4.x;             CPP[o+1]=a;
  a+=e4.y;             CPP[o+2]=a;
  a+=e4.z;             CPP[o+3]=a;
  a=bn;                CPN[o+0]=a;
  a+=n4.x;             CPN[o+1]=a;
  a+=n4.y;             CPN[o+2]=a;
  a+=n4.z;             CPN[o+3]=a;
  if(t==1023){CPP[(size_t)p*4097+4096]=sp[1023]; CPN[(size_t)p*4097+4096]=sn[1023];}
}

// ---------- layer0 relative tables: 2 chunks per wave, width-32 rows ---------
__global__ void __launch_bounds__(256) ktables0(const unsigned* __restrict__ perm,
    const float* __restrict__ eP, const float* __restrict__ eN,
    const float* __restrict__ hp, float* __restrict__ TPP, float* __restrict__ TPN,
    float* __restrict__ rawP, float* __restrict__ rawN){
  int gw=(blockIdx.x*256+threadIdx.x)>>6;   // 0..2047
  int lane=threadIdx.x&63, half=lane>>5, ch=lane&31;
  int cglob=gw*2+half;
  int p=cglob>>8, c=cglob&255;
  float aP=0.f,aN=0.f;
  for(int q=0;q<16;q++){
    int r=c*16+q;
    size_t ro=(size_t)p*N_+r;
    float ep=eP[ro],en=eN[ro];
    unsigned pr=perm[ro];
    float hv=hp[((size_t)p*N_+pr)*32+ch];
    size_t to=((size_t)p*4097+r)*32+ch;
    TPP[to]=aP; TPN[to]=aN;
    aP+=ep*hv; aN+=en*hv;
  }
  size_t bo=((size_t)p*256+c)*32+ch;
  rawP[bo]=aP; rawN[bo]=aN;
}

// ---------- layer1 relative tables: wave per chunk, width-64 rows ------------
__global__ void __launch_bounds__(256) ktables1(const unsigned* __restrict__ perm,
    const float* __restrict__ eP, const float* __restrict__ eN,
    const float* __restrict__ hp, float* __restrict__ TPP, float* __restrict__ TPN,
    float* __restrict__ rawP, float* __restrict__ rawN){
  int wid=(blockIdx.x*256+threadIdx.x)>>6;   // 0..1023
  int lane=threadIdx.x&63;
  int p=wid>>8, c=wid&255;
  float aP=0.f,aN=0.f;
  for(int q=0;q<16;q++){
    int r=c*16+q;
    size_t ro=(size_t)p*N_+r;
    float ep=eP[ro],en=eN[ro];
    unsigned pr=perm[ro];
    float hv=hp[((size_t)p*N_+pr)*64+lane];
    size_t to=((size_t)p*4097+r)*64+lane;
    TPP[to]=aP; TPN[to]=aN;
    aP+=ep*hv; aN+=en*hv;
  }
  size_t bo=((size_t)p*256+c)*64+lane;
  rawP[bo]=aP; rawN[bo]=aN;
}

// ---------- scan chunk sums -> bases; totals -> table row 4096 ---------------
template<int D>
__global__ void __launch_bounds__(256) kscan(const float* __restrict__ rawP,
    const float* __restrict__ rawN, float* __restrict__ bP, float* __restrict__ bN,
    float* __restrict__ TPP, float* __restrict__ TPN){
  extern __shared__ float sm[];   // 256*D
  int p=blockIdx.x, tid=threadIdx.x;
  for(int pass=0;pass<2;pass++){
    const float* src=pass?rawN:rawP;
    float* dst=pass?bN:bP;
    float* tp=pass?TPN:TPP;
    __syncthreads();
    for(int i=tid;i<256*D;i+=256){
      sm[i]=src[(size_t)p*256*D+i];
    }
    __syncthreads();
    if(tid<D){
      float r=0.f;
      for(int c=0;c<256;c++){
        dst[((size_t)p*257+c)*D+tid]=r;
        r+=sm[c*D+tid];
      }
      dst[((size_t)p*257+256)*D+tid]=0.f;      // base for lo==4096
      tp[((size_t)p*4097+4096)*D+tid]=r;       // absolute channel totals
    }
  }
}

// ---------- layer0 row eval: 2 rows per wave, 3-level ballot search ----------
__global__ void __launch_bounds__(256) keval0(const float* __restrict__ ss,
                       const float* __restrict__ sv,
                       const float* __restrict__ bP, const float* __restrict__ bN,
                       const float* __restrict__ TPP, const float* __restrict__ TPN,
                       const float* __restrict__ CPP, const float* __restrict__ CPN,
                       const float* __restrict__ bias, float* __restrict__ out){
  int gw=(blockIdx.x*256+threadIdx.x)>>6;   // 0..32767
  int lane=threadIdx.x&63, half=lane>>5, ch=lane&31;
  int row=gw*2+half;
  int p=row>>12, i=row&4095;
  int b=p>>2, h=p&3;
  const float* svp=sv+(size_t)p*N_;
  float ssrc=ss[(size_t)p*N_+i];
  float m=svp[4095];
  float xx=ssrc+m;
  float M=xx>0.f?xx:0.2f*xx;
  float fpos=expf(xx-M),fneg=expf(0.2f*xx-M);
  float th=-ssrc;
  // level1: 32 samples of block-last (stride 128)
  float s1v=svp[ch*128+127];
  unsigned long long bal=__ballot(s1v<=th);
  int c1=half?(int)__popcll(bal>>32):(int)__popcll(bal&0xFFFFFFFFull);
  int lo;
  if(c1>=32){ lo=4096; }
  else{
    float s2v=svp[c1*128+ch*4+3];
    unsigned long long bal2=__ballot(s2v<=th);
    int c2=half?(int)__popcll(bal2>>32):(int)__popcll(bal2&0xFFFFFFFFull);
    int base=c1*128+c2*4;
    float4 qv=*((const float4*)(svp+base));
    int c3=(qv.x<=th)+(qv.y<=th)+(qv.z<=th)+(qv.w<=th);
    lo=base+c3;
  }
  int c=lo>>4;
  float relP=TPP[((size_t)p*4097+lo)*32+ch];
  float relN=TPN[((size_t)p*4097+lo)*32+ch];
  float baP=bP[((size_t)p*257+c)*32+ch];
  float baN=bN[((size_t)p*257+c)*32+ch];
  float tot=TPP[((size_t)p*4097+4096)*32+ch];
  float CPl=CPP[(size_t)p*4097+lo];
  float CNl=CPN[(size_t)p*4097+lo];
  float CT =CPP[(size_t)p*4097+4096];
  float denom=fpos*(CT-CPl)+fneg*CNl;
  float v=fpos*(tot-(baP+relP))+fneg*(baN+relN);
  float r=v/denom+bias[ch];
  r=r>0.f?r:expm1f(r);
  out[((size_t)(b*N_+i))*128+h*32+ch]=r;
}

// ---------- layer1 row eval: wave per row, width-64 --------------------------
__global__ void __launch_bounds__(256) keval1(const float* __restrict__ ss,
                       const float* __restrict__ sv,
                       const float* __restrict__ bP, const float* __restrict__ bN,
                       const float* __restrict__ TPP, const float* __restrict__ TPN,
                       const float* __restrict__ CPP, const float* __restrict__ CPN,
                       const float* __restrict__ bias, float* __restrict__ out){
  int wid=(blockIdx.x*256+threadIdx.x)>>6;   // p*4096+i
  int lane=threadIdx.x&63;
  int p=wid>>12, i=wid&4095;
  const float* svp=sv+(size_t)p*N_;
  float ssrc=ss[(size_t)p*N_+i];
  float m=svp[4095];
  float xx=ssrc+m;
  float M=xx>0.f?xx:0.2f*xx;
  float fpos=expf(xx-M),fneg=expf(0.2f*xx-M);
  float th=-ssrc;
  float s1v=svp[lane*64+63];
  int c1=(int)__popcll(__ballot(s1v<=th));
  int lo;
  if(c1>=64){ lo=4096; }
  else{
    float s2v=svp[c1*64+lane];
    lo=c1*64+(int)__popcll(__ballot(s2v<=th));
  }
  int c=lo>>4;
  float relP=TPP[((size_t)p*4097+lo)*64+lane];
  float relN=TPN[((size_t)p*4097+lo)*64+lane];
  float baP=bP[((size_t)p*257+c)*64+lane];
  float baN=bN[((size_t)p*257+c)*64+lane];
  float tot=TPP[((size_t)p*4097+4096)*64+lane];
  float CPl=CPP[(size_t)p*4097+lo];
  float CNl=CPN[(size_t)p*4097+lo];
  float CT =CPP[(size_t)p*4097+4096];
  float denom=fpos*(CT-CPl)+fneg*CNl;
  float v=fpos*(tot-(baP+relP))+fneg*(baN+relN);
  out[((size_t)p*N_+i)*64+lane]=v/denom+bias[lane];
}

extern "C" void kernel_launch(void* const* d_in, const int* in_sizes, int n_in,
                              void* d_out, int out_size, void* d_ws, size_t ws_size,
                              hipStream_t stream) {
  const float* x  =(const float*)d_in[0];
  const float* w0 =(const float*)d_in[1];
  const float* as0=(const float*)d_in[2];
  const float* ad0=(const float*)d_in[3];
  const float* b0 =(const float*)d_in[4];
  const float* w1 =(const float*)d_in[5];
  const float* as1=(const float*)d_in[6];
  const float* ad1=(const float*)d_in[7];
  const float* b1 =(const float*)d_in[8];
  float* ws=(float*)d_ws;
  float* out=(float*)d_out;

  float* st0 = ws+OFF_STATS0;
  float* st1 = ws+OFF_STATS1;
  float* hp0 = ws+OFF_HP0;
  float* elu = ws+OFF_ELU;
  float* ss0 = ws+OFF_SS0;  float* sd0 = ws+OFF_SD0;
  unsigned long long* runs0=(unsigned long long*)(ws+OFF_RUNS0);
  float* sv0 = ws+OFF_SV0;
  unsigned* pm0=(unsigned*)(ws+OFF_PM0);
  float* eP0 = ws+OFF_EP0;  float* eN0 = ws+OFF_EN0;
  float* cP0 = ws+OFF_CPP0; float* cN0 = ws+OFF_CPN0;
  float* rP0 = ws+OFF_RAWP0; float* rN0 = ws+OFF_RAWN0;
  float* bP0 = ws+OFF_BP0;  float* bN0 = ws+OFF_BN0;
  float* tP0 = ws+OFF_TPP0; float* tN0 = ws+OFF_TPN0;
  float* hp1 = ws+OFF_HP1;
  float* ss1 = ws+OFF_SS1;  float* sd1 = ws+OFF_SD1;
  unsigned long long* runs1=(unsigned long long*)(ws+OFF_RUNS1);
  float* sv1 = ws+OFF_SV1;
  unsigned* pm1=(unsigned*)(ws+OFF_PM1);
  float* eP1 = ws+OFF_EP1;  float* eN1 = ws+OFF_EN1;
  float* cP1 = ws+OFF_CPP1; float* cN1 = ws+OFF_CPN1;
  float* rP1 = ws+OFF_RAWP1; float* rN1 = ws+OFF_RAWN1;
  float* bP1 = ws+OFF_BP1;  float* bN1 = ws+OFF_BN1;
  float* tP1 = ws+OFF_TPP1; float* tN1 = ws+OFF_TPN1;

  hipMemsetAsync(d_ws, 0, 1536*sizeof(float), stream);

  // ---- layer 0 ----
  kstats<64><<<128,256,0,stream>>>(x,st0);
  kproj0<<<256,256,0,stream>>>(x,st0,w0,as0,ad0,hp0,ss0,sd0);
  ksort_runs<<<64,256,0,stream>>>(sd0,runs0);
  kmerge<<<64,1024,0,stream>>>(runs0,sv0,pm0,eP0,eN0);
  kcounts<<<16,1024,0,stream>>>(eP0,eN0,cP0,cN0);
  ktables0<<<512,256,0,stream>>>(pm0,eP0,eN0,hp0,tP0,tN0,rP0,rN0);
  kscan<32><<<16,256,256*32*4,stream>>>(rP0,rN0,bP0,bN0,tP0,tN0);
  keval0<<<8192,256,0,stream>>>(ss0,sv0,bP0,bN0,tP0,tN0,cP0,cN0,b0,elu);
  // ---- layer 1 ----
  kstats<128><<<128,256,0,stream>>>(elu,st1);
  kproj1<<<256,256,0,stream>>>(elu,st1,w1,as1,ad1,hp1,ss1,sd1);
  ksort_runs<<<16,256,0,stream>>>(sd1,runs1);
  kmerge<<<16,1024,0,stream>>>(runs1,sv1,pm1,eP1,eN1);
  kcounts<<<4,1024,0,stream>>>(eP1,eN1,cP1,cN1);
  ktables1<<<256,256,0,stream>>>(pm1,eP1,eN1,hp1,tP1,tN1,rP1,rN1);
  kscan<64><<<4,256,256*64*4,stream>>>(rP1,rN1,bP1,bN1,tP1,tN1);
  keval1<<<4096,256,0,stream>>>(ss1,sv1,bP1,bN1,tP1,tN1,cP1,cN1,b1,out);
}

// Round 12
// 232.503 us; speedup vs baseline: 1.4349x; 1.0040x over previous
//
#include <hip/hip_runtime.h>
#include <math.h>

#define N_ 4096

// ---------------- workspace float offsets -----------------------------------
static constexpr size_t OFF_HP0    = 2048;     // [16][4096][32]; ELU aliases
static constexpr size_t OFF_ELU    = 2048;     // [4][4096][128]
static constexpr size_t OFF_SS0    = 2099200;
static constexpr size_t OFF_SD0    = 2164736;
static constexpr size_t OFF_RUNS0  = 2230272;  // u64[16][4096]
static constexpr size_t OFF_SV0    = 2361344;
static constexpr size_t OFF_PM0    = 2426880;
static constexpr size_t OFF_EP0    = 2492416;
static constexpr size_t OFF_EN0    = 2557952;
static constexpr size_t OFF_CPP0   = 2623488;  // [16][4097] scalar count prefixes
static constexpr size_t OFF_CPN0   = 2689040;
static constexpr size_t OFF_RAWP0  = 2754592;  // [16][256][32]
static constexpr size_t OFF_RAWN0  = 2885664;
static constexpr size_t OFF_BP0    = 3016736;  // [16][257][32]
static constexpr size_t OFF_BN0    = 3148320;
static constexpr size_t OFF_TPP0   = 3279904;  // [16][4097][32]
static constexpr size_t OFF_TPN0   = 5377568;  // ends 7475232
// ---- layer1 aliases TPP0/TPN0 region (dead after keval0) ----
static constexpr size_t OFF_HP1    = 3279904;  // [4][4096][64]
static constexpr size_t OFF_SS1    = 4328480;
static constexpr size_t OFF_SD1    = 4344864;
static constexpr size_t OFF_RUNS1  = 4361248;  // u64[4][4096]
static constexpr size_t OFF_SV1    = 4394016;
static constexpr size_t OFF_PM1    = 4410400;
static constexpr size_t OFF_EP1    = 4426784;
static constexpr size_t OFF_EN1    = 4443168;
static constexpr size_t OFF_CPP1   = 4459552;  // [4][4097]
static constexpr size_t OFF_CPN1   = 4475940;
static constexpr size_t OFF_RAWP1  = 4492328;  // [4][256][64]
static constexpr size_t OFF_RAWN1  = 4557864;
static constexpr size_t OFF_BP1    = 4623400;  // [4][257][64]
static constexpr size_t OFF_BN1    = 4689192;
static constexpr size_t OFF_TPP1   = 4754984;  // [4][4097][64]
static constexpr size_t OFF_TPN1   = 5803816;  // ends 6852648
// ---- two-phase stats partials (no memset needed; written unconditionally) --
static constexpr size_t OFF_S0P    = 6852648;  // [4][32][64][2]  = 16384
static constexpr size_t OFF_S1P    = 6869032;  // [4][32][128][2] = 32768; end 6901800 ~27.6 MB

__device__ __forceinline__ unsigned f2s(float f){
  unsigned u=__float_as_uint(f);
  return u^((u&0x80000000u)?0xFFFFFFFFu:0x80000000u);
}
__device__ __forceinline__ float s2f(unsigned s){
  unsigned u=(s&0x80000000u)?(s^0x80000000u):~s;
  return __uint_as_float(u);
}

// ---------- partial stats (coalesced); per-block partials, NO atomics --------
template<int C>
__global__ void kstats(const float* __restrict__ x, float* __restrict__ statsP){
  int blk=blockIdx.x; int b=blk>>5;
  int tid=threadIdx.x;
  const int RPT=256/C;
  const int IT=128/RPT;
  int c=tid%C, rl=tid/C;
  const float* xb=x+(size_t)b*N_*C;
  float s1=0.f,s2=0.f;
  int r0=(blk&31)*128+rl;
  for(int i=0;i<IT;i++){
    float v=xb[(size_t)(r0+i*RPT)*C+c];
    s1+=v;s2+=v*v;
  }
  __shared__ float sh1[256],sh2[256];
  sh1[tid]=s1;sh2[tid]=s2;__syncthreads();
  if(tid<C){
    float a1=0.f,a2=0.f;
    for(int g=0;g<RPT;g++){a1+=sh1[g*C+tid];a2+=sh2[g*C+tid];}
    statsP[((size_t)blk*C+tid)*2+0]=a1;
    statsP[((size_t)blk*C+tid)*2+1]=a2;
  }
}

// ---------- layer0 projection; h wave-uniform -> LDS broadcast (no conflict) -
__global__ void __launch_bounds__(256) kproj0(
                       const float* __restrict__ x, const float* __restrict__ statsP,
                       const float* __restrict__ w0, const float* __restrict__ asrc,
                       const float* __restrict__ adst, float* __restrict__ hp,
                       float* __restrict__ ss, float* __restrict__ sd){
  __shared__ float4 w4[2048];
  __shared__ float4 av4[64];
  __shared__ float mean[64],rstd[64];
  int tid=threadIdx.x;
  const float4* wg=(const float4*)w0;
  for(int i=tid;i<2048;i+=256) w4[i]=wg[i];
  if(tid<32) av4[tid]=((const float4*)asrc)[tid];
  else if(tid<64) av4[tid]=((const float4*)adst)[tid-32];
  int gid=blockIdx.x*256+tid;
  int b=gid>>14, h=(gid>>12)&3, n=gid&4095;   // wave-uniform h
  if(tid<64){
    float s1=0.f,s2=0.f;
    for(int g=0;g<32;g++){
      s1+=statsP[((size_t)(b*32+g)*64+tid)*2+0];
      s2+=statsP[((size_t)(b*32+g)*64+tid)*2+1];
    }
    float mu=s1*(1.0f/N_);
    float var=s2*(1.0f/N_)-mu*mu;
    mean[tid]=mu; rstd[tid]=rsqrtf(var+1e-5f);
  }
  __syncthreads();
  const float4* hr4=(const float4*)(x+((size_t)(b*N_+n))*64);
  float4 acc[8];
  #pragma unroll
  for(int q=0;q<8;q++) acc[q]=make_float4(0.f,0.f,0.f,0.f);
  #pragma unroll
  for(int ch=0;ch<4;ch++){
    float4 t[4];
    #pragma unroll
    for(int j=0;j<4;j++) t[j]=hr4[ch*4+j];
    #pragma unroll
    for(int j=0;j<4;j++){
      int d0=ch*16+j*4;
      float hv[4];
      hv[0]=(t[j].x-mean[d0+0])*rstd[d0+0];
      hv[1]=(t[j].y-mean[d0+1])*rstd[d0+1];
      hv[2]=(t[j].z-mean[d0+2])*rstd[d0+2];
      hv[3]=(t[j].w-mean[d0+3])*rstd[d0+3];
      #pragma unroll
      for(int dd=0;dd<4;dd++){
        float hvv=hv[dd];
        #pragma unroll
        for(int q=0;q<8;q++){
          float4 wv=w4[(h*64+d0+dd)*8+q];
          acc[q].x+=hvv*wv.x;acc[q].y+=hvv*wv.y;acc[q].z+=hvv*wv.z;acc[q].w+=hvv*wv.w;
        }
      }
    }
  }
  float ssv=0.f,sdv=0.f;
  #pragma unroll
  for(int q=0;q<8;q++){
    float4 a1=av4[h*8+q],a2=av4[32+h*8+q];
    ssv+=acc[q].x*a1.x+acc[q].y*a1.y+acc[q].z*a1.z+acc[q].w*a1.w;
    sdv+=acc[q].x*a2.x+acc[q].y*a2.y+acc[q].z*a2.z+acc[q].w*a2.w;
  }
  int p=b*4+h;
  float4* o4=(float4*)(hp+((size_t)p*N_+n)*32);
  #pragma unroll
  for(int q=0;q<8;q++) o4[q]=acc[q];
  ss[(size_t)p*N_+n]=ssv; sd[(size_t)p*N_+n]=sdv;
}

// ---------- layer1 projection; q4 wave-uniform -> LDS broadcast --------------
__global__ void __launch_bounds__(256) kproj1(
                       const float* __restrict__ x, const float* __restrict__ statsP,
                       const float* __restrict__ w1, const float* __restrict__ asrc,
                       const float* __restrict__ adst, float* __restrict__ hp,
                       float* __restrict__ ss, float* __restrict__ sd){
  __shared__ float4 w4[2048];
  __shared__ float wa[128],wd[128],mean[128],rstd[128];
  int tid=threadIdx.x;
  const float4* wg=(const float4*)w1;
  for(int i=tid;i<2048;i+=256) w4[i]=wg[i];
  int gid=blockIdx.x*256+tid;
  int b=gid>>14, q4=(gid>>12)&3, n=gid&4095;  // wave-uniform q4
  if(tid<128){
    float s1a=0.f,s2a=0.f;
    for(int k=0;k<64;k++){float wv=w1[tid*64+k];s1a+=wv*asrc[k];s2a+=wv*adst[k];}
    wa[tid]=s1a;wd[tid]=s2a;
    float s1=0.f,s2=0.f;
    for(int g=0;g<32;g++){
      s1+=statsP[((size_t)(b*32+g)*128+tid)*2+0];
      s2+=statsP[((size_t)(b*32+g)*128+tid)*2+1];
    }
    float mu=s1*(1.0f/N_);
    float var=s2*(1.0f/N_)-mu*mu;
    mean[tid]=mu; rstd[tid]=rsqrtf(var+1e-5f);
  }
  __syncthreads();
  const float4* hr4=(const float4*)(x+((size_t)(b*N_+n))*128);
  float4 acc[4];
  #pragma unroll
  for(int q=0;q<4;q++) acc[q]=make_float4(0.f,0.f,0.f,0.f);
  float s1=0.f,s2=0.f;
  #pragma unroll
  for(int ch=0;ch<8;ch++){
    float4 t[4];
    #pragma unroll
    for(int j=0;j<4;j++) t[j]=hr4[ch*4+j];
    #pragma unroll
    for(int j=0;j<4;j++){
      int d0=ch*16+j*4;
      float hv[4];
      hv[0]=(t[j].x-mean[d0+0])*rstd[d0+0];
      hv[1]=(t[j].y-mean[d0+1])*rstd[d0+1];
      hv[2]=(t[j].z-mean[d0+2])*rstd[d0+2];
      hv[3]=(t[j].w-mean[d0+3])*rstd[d0+3];
      #pragma unroll
      for(int dd=0;dd<4;dd++){
        float hvv=hv[dd]; int d=d0+dd;
        s1+=hvv*wa[d]; s2+=hvv*wd[d];
        #pragma unroll
        for(int q=0;q<4;q++){
          float4 wv=w4[d*16+q4*4+q];
          acc[q].x+=hvv*wv.x;acc[q].y+=hvv*wv.y;acc[q].z+=hvv*wv.z;acc[q].w+=hvv*wv.w;
        }
      }
    }
  }
  float4* o4=(float4*)(hp+((size_t)(b*N_+n))*64+q4*16);
  #pragma unroll
  for(int q=0;q<4;q++) o4[q]=acc[q];
  if(q4==0){
    ss[(size_t)b*N_+n]=s1;sd[(size_t)b*N_+n]=s2;
  }
}

// ---------- sort runs of 1024 (packed u64 = key<<32 | orig_idx) --------------
__global__ void __launch_bounds__(256) ksort_runs(const float* __restrict__ sdst,
                                                  unsigned long long* __restrict__ runs){
  __shared__ unsigned long long sm[1024];
  int p=blockIdx.x>>2, run=blockIdx.x&3;
  int tid=threadIdx.x;
  const float* s=sdst+(size_t)p*N_+run*1024;
  for(int l=tid;l<1024;l+=256){
    unsigned key=f2s(s[l]);
    sm[l]=((unsigned long long)key<<32)|(unsigned)(run*1024+l);
  }
  for(unsigned k=2;k<=1024u;k<<=1)
    for(unsigned j=k>>1;j>0;j>>=1){
      __syncthreads();
      for(unsigned t=tid;t<512u;t+=256u){
        unsigned i=((t&~(j-1))<<1)|(t&(j-1));
        unsigned q=i|j;
        bool up=((i&k)==0);
        unsigned long long a=sm[i],b=sm[q];
        if((a>b)==up){sm[i]=b;sm[q]=a;}
      }
    }
  __syncthreads();
  unsigned long long* rg=runs+(size_t)p*N_+run*1024;
  for(int l=tid;l<1024;l+=256) rg[l]=sm[l];
}

// ---------- merge 4 sorted runs by rank (binary search in LDS) ---------------
__global__ void __launch_bounds__(1024) kmerge(const unsigned long long* __restrict__ runs,
    float* __restrict__ sv, unsigned* __restrict__ perm,
    float* __restrict__ eP, float* __restrict__ eN){
  __shared__ unsigned long long sm[4096];
  int p=blockIdx.x>>2, cg=blockIdx.x&3;
  int tid=threadIdx.x;
  const unsigned long long* rg=runs+(size_t)p*N_;
  for(int l=tid;l<4096;l+=1024) sm[l]=rg[l];
  __syncthreads();
  unsigned long long e=sm[cg*1024+tid];
  int rank=tid;
  #pragma unroll
  for(int o=0;o<4;o++){
    if(o==cg) continue;
    const unsigned long long* base=sm+o*1024;
    int lo=0,hi=1024;
    while(lo<hi){int mid=(lo+hi)>>1; if(base[mid]<e) lo=mid+1; else hi=mid;}
    rank+=lo;
  }
  unsigned long long mk=sm[1023];
  if(sm[2047]>mk) mk=sm[2047];
  if(sm[3071]>mk) mk=sm[3071];
  if(sm[4095]>mk) mk=sm[4095];
  float m=s2f((unsigned)(mk>>32));
  float v=s2f((unsigned)(e>>32));
  size_t o=(size_t)p*N_+rank;
  sv[o]=v;
  perm[o]=(unsigned)(e&0xffffffffu);
  eP[o]=expf(v-m);
  eN[o]=expf(0.2f*(v-m));
}

// ---------- absolute scalar count prefixes per p (block scan) ----------------
__global__ void __launch_bounds__(1024) kcounts(const float* __restrict__ eP,
    const float* __restrict__ eN, float* __restrict__ CPP, float* __restrict__ CPN){
  __shared__ float sp[1024],sn[1024];
  int p=blockIdx.x, t=threadIdx.x;
  float4 e4=((const float4*)(eP+(size_t)p*N_))[t];
  float4 n4=((const float4*)(eN+(size_t)p*N_))[t];
  float lp=e4.x+e4.y+e4.z+e4.w;
  float ln=n4.x+n4.y+n4.z+n4.w;
  sp[t]=lp; sn[t]=ln; __syncthreads();
  for(int off=1;off<1024;off<<=1){
    float vp=(t>=off)?sp[t-off]:0.f;
    float vn=(t>=off)?sn[t-off]:0.f;
    __syncthreads();
    sp[t]+=vp; sn[t]+=vn;
    __syncthreads();
  }
  float bp=sp[t]-lp, bn=sn[t]-ln;   // exclusive base for this thread's 4
  size_t o=(size_t)p*4097+t*4;
  float a=bp;          CPP[o+0]=a;
  a+=e4.x;             CPP[o+1]=a;
  a+=e4.y;             CPP[o+2]=a;
  a+=e4.z;             CPP[o+3]=a;
  a=bn;                CPN[o+0]=a;
  a+=n4.x;             CPN[o+1]=a;
  a+=n4.y;             CPN[o+2]=a;
  a+=n4.z;             CPN[o+3]=a;
  if(t==1023){CPP[(size_t)p*4097+4096]=sp[1023]; CPN[(size_t)p*4097+4096]=sn[1023];}
}

// ---------- layer0 relative tables: 2 chunks per wave, width-32 rows ---------
__global__ void __launch_bounds__(256) ktables0(const unsigned* __restrict__ perm,
    const float* __restrict__ eP, const float* __restrict__ eN,
    const float* __restrict__ hp, float* __restrict__ TPP, float* __restrict__ TPN,
    float* __restrict__ rawP, float* __restrict__ rawN){
  int gw=(blockIdx.x*256+threadIdx.x)>>6;   // 0..2047
  int lane=threadIdx.x&63, half=lane>>5, ch=lane&31;
  int cglob=gw*2+half;
  int p=cglob>>8, c=cglob&255;
  float aP=0.f,aN=0.f;
  for(int q=0;q<16;q++){
    int r=c*16+q;
    size_t ro=(size_t)p*N_+r;
    float ep=eP[ro],en=eN[ro];
    unsigned pr=perm[ro];
    float hv=hp[((size_t)p*N_+pr)*32+ch];
    size_t to=((size_t)p*4097+r)*32+ch;
    TPP[to]=aP; TPN[to]=aN;
    aP+=ep*hv; aN+=en*hv;
  }
  size_t bo=((size_t)p*256+c)*32+ch;
  rawP[bo]=aP; rawN[bo]=aN;
}

// ---------- layer1 relative tables: wave per chunk, width-64 rows ------------
__global__ void __launch_bounds__(256) ktables1(const unsigned* __restrict__ perm,
    const float* __restrict__ eP, const float* __restrict__ eN,
    const float* __restrict__ hp, float* __restrict__ TPP, float* __restrict__ TPN,
    float* __restrict__ rawP, float* __restrict__ rawN){
  int wid=(blockIdx.x*256+threadIdx.x)>>6;   // 0..1023
  int lane=threadIdx.x&63;
  int p=wid>>8, c=wid&255;
  float aP=0.f,aN=0.f;
  for(int q=0;q<16;q++){
    int r=c*16+q;
    size_t ro=(size_t)p*N_+r;
    float ep=eP[ro],en=eN[ro];
    unsigned pr=perm[ro];
    float hv=hp[((size_t)p*N_+pr)*64+lane];
    size_t to=((size_t)p*4097+r)*64+lane;
    TPP[to]=aP; TPN[to]=aN;
    aP+=ep*hv; aN+=en*hv;
  }
  size_t bo=((size_t)p*256+c)*64+lane;
  rawP[bo]=aP; rawN[bo]=aN;
}

// ---------- scan chunk sums -> bases; totals -> table row 4096 ---------------
template<int D>
__global__ void __launch_bounds__(256) kscan(const float* __restrict__ rawP,
    const float* __restrict__ rawN, float* __restrict__ bP, float* __restrict__ bN,
    float* __restrict__ TPP, float* __restrict__ TPN){
  extern __shared__ float sm[];   // 256*D
  int p=blockIdx.x, tid=threadIdx.x;
  for(int pass=0;pass<2;pass++){
    const float* src=pass?rawN:rawP;
    float* dst=pass?bN:bP;
    float* tp=pass?TPN:TPP;
    __syncthreads();
    for(int i=tid;i<256*D;i+=256){
      sm[i]=src[(size_t)p*256*D+i];
    }
    __syncthreads();
    if(tid<D){
      float r=0.f;
      for(int c=0;c<256;c++){
        dst[((size_t)p*257+c)*D+tid]=r;
        r+=sm[c*D+tid];
      }
      dst[((size_t)p*257+256)*D+tid]=0.f;      // base for lo==4096
      tp[((size_t)p*4097+4096)*D+tid]=r;       // absolute channel totals
    }
  }
}

// ---------- layer0 row eval: 2 rows per wave, 3-level ballot search ----------
__global__ void __launch_bounds__(256) keval0(const float* __restrict__ ss,
                       const float* __restrict__ sv,
                       const float* __restrict__ bP, const float* __restrict__ bN,
                       const float* __restrict__ TPP, const float* __restrict__ TPN,
                       const float* __restrict__ CPP, const float* __restrict__ CPN,
                       const float* __restrict__ bias, float* __restrict__ out){
  int gw=(blockIdx.x*256+threadIdx.x)>>6;   // 0..32767
  int lane=threadIdx.x&63, half=lane>>5, ch=lane&31;
  int row=gw*2+half;
  int p=row>>12, i=row&4095;
  int b=p>>2, h=p&3;
  const float* svp=sv+(size_t)p*N_;
  float ssrc=ss[(size_t)p*N_+i];
  float m=svp[4095];
  float xx=ssrc+m;
  float M=xx>0.f?xx:0.2f*xx;
  float fpos=expf(xx-M),fneg=expf(0.2f*xx-M);
  float th=-ssrc;
  // level1: 32 samples of block-last (stride 128)
  float s1v=svp[ch*128+127];
  unsigned long long bal=__ballot(s1v<=th);
  int c1=half?(int)__popcll(bal>>32):(int)__popcll(bal&0xFFFFFFFFull);
  int lo;
  if(c1>=32){ lo=4096; }
  else{
    float s2v=svp[c1*128+ch*4+3];
    unsigned long long bal2=__ballot(s2v<=th);
    int c2=half?(int)__popcll(bal2>>32):(int)__popcll(bal2&0xFFFFFFFFull);
    int base=c1*128+c2*4;
    float4 qv=*((const float4*)(svp+base));
    int c3=(qv.x<=th)+(qv.y<=th)+(qv.z<=th)+(qv.w<=th);
    lo=base+c3;
  }
  int c=lo>>4;
  float relP=TPP[((size_t)p*4097+lo)*32+ch];
  float relN=TPN[((size_t)p*4097+lo)*32+ch];
  float baP=bP[((size_t)p*257+c)*32+ch];
  float baN=bN[((size_t)p*257+c)*32+ch];
  float tot=TPP[((size_t)p*4097+4096)*32+ch];
  float CPl=CPP[(size_t)p*4097+lo];
  float CNl=CPN[(size_t)p*4097+lo];
  float CT =CPP[(size_t)p*4097+4096];
  float denom=fpos*(CT-CPl)+fneg*CNl;
  float v=fpos*(tot-(baP+relP))+fneg*(baN+relN);
  float r=v/denom+bias[ch];
  r=r>0.f?r:expm1f(r);
  out[((size_t)(b*N_+i))*128+h*32+ch]=r;
}

// ---------- layer1 row eval: wave per row, width-64 --------------------------
__global__ void __launch_bounds__(256) keval1(const float* __restrict__ ss,
                       const float* __restrict__ sv,
                       const float* __restrict__ bP, const float* __restrict__ bN,
                       const float* __restrict__ TPP, const float* __restrict__ TPN,
                       const float* __restrict__ CPP, const float* __restrict__ CPN,
                       const float* __restrict__ bias, float* __restrict__ out){
  int wid=(blockIdx.x*256+threadIdx.x)>>6;   // p*4096+i
  int lane=threadIdx.x&63;
  int p=wid>>12, i=wid&4095;
  const float* svp=sv+(size_t)p*N_;
  float ssrc=ss[(size_t)p*N_+i];
  float m=svp[4095];
  float xx=ssrc+m;
  float M=xx>0.f?xx:0.2f*xx;
  float fpos=expf(xx-M),fneg=expf(0.2f*xx-M);
  float th=-ssrc;
  float s1v=svp[lane*64+63];
  int c1=(int)__popcll(__ballot(s1v<=th));
  int lo;
  if(c1>=64){ lo=4096; }
  else{
    float s2v=svp[c1*64+lane];
    lo=c1*64+(int)__popcll(__ballot(s2v<=th));
  }
  int c=lo>>4;
  float relP=TPP[((size_t)p*4097+lo)*64+lane];
  float relN=TPN[((size_t)p*4097+lo)*64+lane];
  float baP=bP[((size_t)p*257+c)*64+lane];
  float baN=bN[((size_t)p*257+c)*64+lane];
  float tot=TPP[((size_t)p*4097+4096)*64+lane];
  float CPl=CPP[(size_t)p*4097+lo];
  float CNl=CPN[(size_t)p*4097+lo];
  float CT =CPP[(size_t)p*4097+4096];
  float denom=fpos*(CT-CPl)+fneg*CNl;
  float v=fpos*(tot-(baP+relP))+fneg*(baN+relN);
  out[((size_t)p*N_+i)*64+lane]=v/denom+bias[lane];
}

extern "C" void kernel_launch(void* const* d_in, const int* in_sizes, int n_in,
                              void* d_out, int out_size, void* d_ws, size_t ws_size,
                              hipStream_t stream) {
  const float* x  =(const float*)d_in[0];
  const float* w0 =(const float*)d_in[1];
  const float* as0=(const float*)d_in[2];
  const float* ad0=(const float*)d_in[3];
  const float* b0 =(const float*)d_in[4];
  const float* w1 =(const float*)d_in[5];
  const float* as1=(const float*)d_in[6];
  const float* ad1=(const float*)d_in[7];
  const float* b1 =(const float*)d_in[8];
  float* ws=(float*)d_ws;
  float* out=(float*)d_out;

  float* s0p = ws+OFF_S0P;
  float* s1p = ws+OFF_S1P;
  float* hp0 = ws+OFF_HP0;
  float* elu = ws+OFF_ELU;
  float* ss0 = ws+OFF_SS0;  float* sd0 = ws+OFF_SD0;
  unsigned long long* runs0=(unsigned long long*)(ws+OFF_RUNS0);
  float* sv0 = ws+OFF_SV0;
  unsigned* pm0=(unsigned*)(ws+OFF_PM0);
  float* eP0 = ws+OFF_EP0;  float* eN0 = ws+OFF_EN0;
  float* cP0 = ws+OFF_CPP0; float* cN0 = ws+OFF_CPN0;
  float* rP0 = ws+OFF_RAWP0; float* rN0 = ws+OFF_RAWN0;
  float* bP0 = ws+OFF_BP0;  float* bN0 = ws+OFF_BN0;
  float* tP0 = ws+OFF_TPP0; float* tN0 = ws+OFF_TPN0;
  float* hp1 = ws+OFF_HP1;
  float* ss1 = ws+OFF_SS1;  float* sd1 = ws+OFF_SD1;
  unsigned long long* runs1=(unsigned long long*)(ws+OFF_RUNS1);
  float* sv1 = ws+OFF_SV1;
  unsigned* pm1=(unsigned*)(ws+OFF_PM1);
  float* eP1 = ws+OFF_EP1;  float* eN1 = ws+OFF_EN1;
  float* cP1 = ws+OFF_CPP1; float* cN1 = ws+OFF_CPN1;
  float* rP1 = ws+OFF_RAWP1; float* rN1 = ws+OFF_RAWN1;
  float* bP1 = ws+OFF_BP1;  float* bN1 = ws+OFF_BN1;
  float* tP1 = ws+OFF_TPP1; float* tN1 = ws+OFF_TPN1;

  // ---- layer 0 ----
  kstats<64><<<128,256,0,stream>>>(x,s0p);
  kproj0<<<256,256,0,stream>>>(x,s0p,w0,as0,ad0,hp0,ss0,sd0);
  ksort_runs<<<64,256,0,stream>>>(sd0,runs0);
  kmerge<<<64,1024,0,stream>>>(runs0,sv0,pm0,eP0,eN0);
  kcounts<<<16,1024,0,stream>>>(eP0,eN0,cP0,cN0);
  ktables0<<<512,256,0,stream>>>(pm0,eP0,eN0,hp0,tP0,tN0,rP0,rN0);
  kscan<32><<<16,256,256*32*4,stream>>>(rP0,rN0,bP0,bN0,tP0,tN0);
  keval0<<<8192,256,0,stream>>>(ss0,sv0,bP0,bN0,tP0,tN0,cP0,cN0,b0,elu);
  // ---- layer 1 ----
  kstats<128><<<128,256,0,stream>>>(elu,s1p);
  kproj1<<<256,256,0,stream>>>(elu,s1p,w1,as1,ad1,hp1,ss1,sd1);
  ksort_runs<<<16,256,0,stream>>>(sd1,runs1);
  kmerge<<<16,1024,0,stream>>>(runs1,sv1,pm1,eP1,eN1);
  kcounts<<<4,1024,0,stream>>>(eP1,eN1,cP1,cN1);
  ktables1<<<256,256,0,stream>>>(pm1,eP1,eN1,hp1,tP1,tN1,rP1,rN1);
  kscan<64><<<4,256,256*64*4,stream>>>(rP1,rN1,bP1,bN1,tP1,tN1);
  keval1<<<4096,256,0,stream>>>(ss1,sv1,bP1,bN1,tP1,tN1,cP1,cN1,b1,out);
}

// Round 13
// 231.379 us; speedup vs baseline: 1.4419x; 1.0049x over previous
//
#include <hip/hip_runtime.h>
#include <math.h>

#define N_ 4096

// ---------------- workspace float offsets -----------------------------------
static constexpr size_t OFF_HP0    = 2048;     // [16][4096][32]; ELU aliases
static constexpr size_t OFF_ELU    = 2048;     // [4][4096][128]
static constexpr size_t OFF_SS0    = 2099200;
static constexpr size_t OFF_SD0    = 2164736;
static constexpr size_t OFF_RUNS0  = 2230272;  // u64[16][4096]
static constexpr size_t OFF_SV0    = 2361344;
static constexpr size_t OFF_PM0    = 2426880;
static constexpr size_t OFF_EP0    = 2492416;
static constexpr size_t OFF_EN0    = 2557952;
static constexpr size_t OFF_CPP0   = 2623488;  // [16][4097] scalar count prefixes
static constexpr size_t OFF_CPN0   = 2689040;
static constexpr size_t OFF_RAWP0  = 2754592;  // [16][256][32]
static constexpr size_t OFF_RAWN0  = 2885664;
static constexpr size_t OFF_BP0    = 3016736;  // [16][257][32]
static constexpr size_t OFF_BN0    = 3148320;
static constexpr size_t OFF_TPP0   = 3279904;  // [16][4097][32]
static constexpr size_t OFF_TPN0   = 5377568;  // ends 7475232
// ---- layer1 aliases TPP0/TPN0 region (dead after keval0) ----
static constexpr size_t OFF_HP1    = 3279904;  // [4][4096][64]
static constexpr size_t OFF_SS1    = 4328480;
static constexpr size_t OFF_SD1    = 4344864;
static constexpr size_t OFF_RUNS1  = 4361248;  // u64[4][4096]
static constexpr size_t OFF_SV1    = 4394016;
static constexpr size_t OFF_PM1    = 4410400;
static constexpr size_t OFF_EP1    = 4426784;
static constexpr size_t OFF_EN1    = 4443168;
static constexpr size_t OFF_CPP1   = 4459552;  // [4][4097]
static constexpr size_t OFF_CPN1   = 4475940;
static constexpr size_t OFF_RAWP1  = 4492328;  // [4][256][64]
static constexpr size_t OFF_RAWN1  = 4557864;
static constexpr size_t OFF_BP1    = 4623400;  // [4][257][64]
static constexpr size_t OFF_BN1    = 4689192;
static constexpr size_t OFF_TPP1   = 4754984;  // [4][4097][64]
static constexpr size_t OFF_TPN1   = 5803816;  // ends 6852648
// ---- two-phase stats partials (no memset needed; written unconditionally) --
static constexpr size_t OFF_S0P    = 6852648;  // [4][32][64][2]  = 16384
static constexpr size_t OFF_S1P    = 6869032;  // [4][32][128][2] = 32768; end 6901800 ~27.6 MB

__device__ __forceinline__ unsigned f2s(float f){
  unsigned u=__float_as_uint(f);
  return u^((u&0x80000000u)?0xFFFFFFFFu:0x80000000u);
}
__device__ __forceinline__ float s2f(unsigned s){
  unsigned u=(s&0x80000000u)?(s^0x80000000u):~s;
  return __uint_as_float(u);
}

// ---------- partial stats (coalesced); per-block partials, NO atomics --------
template<int C>
__global__ void kstats(const float* __restrict__ x, float* __restrict__ statsP){
  int blk=blockIdx.x; int b=blk>>5;
  int tid=threadIdx.x;
  const int RPT=256/C;
  const int IT=128/RPT;
  int c=tid%C, rl=tid/C;
  const float* xb=x+(size_t)b*N_*C;
  float s1=0.f,s2=0.f;
  int r0=(blk&31)*128+rl;
  for(int i=0;i<IT;i++){
    float v=xb[(size_t)(r0+i*RPT)*C+c];
    s1+=v;s2+=v*v;
  }
  __shared__ float sh1[256],sh2[256];
  sh1[tid]=s1;sh2[tid]=s2;__syncthreads();
  if(tid<C){
    float a1=0.f,a2=0.f;
    for(int g=0;g<RPT;g++){a1+=sh1[g*C+tid];a2+=sh2[g*C+tid];}
    statsP[((size_t)blk*C+tid)*2+0]=a1;
    statsP[((size_t)blk*C+tid)*2+1]=a2;
  }
}

// ---------- layer0 projection; h wave-uniform; spread stats reduce -----------
__global__ void __launch_bounds__(256) kproj0(
                       const float* __restrict__ x, const float* __restrict__ statsP,
                       const float* __restrict__ w0, const float* __restrict__ asrc,
                       const float* __restrict__ adst, float* __restrict__ hp,
                       float* __restrict__ ss, float* __restrict__ sd){
  __shared__ float4 w4[2048];
  __shared__ float4 av4[64];
  __shared__ float mean[64],rstd[64];
  __shared__ float red1[256],red2[256];
  int tid=threadIdx.x;
  const float4* wg=(const float4*)w0;
  for(int i=tid;i<2048;i+=256) w4[i]=wg[i];
  if(tid<32) av4[tid]=((const float4*)asrc)[tid];
  else if(tid<64) av4[tid]=((const float4*)adst)[tid-32];
  int gid=blockIdx.x*256+tid;
  int b=gid>>14, h=(gid>>12)&3, n=gid&4095;   // wave-uniform h; b block-uniform
  {
    int tc=tid&63, tg=tid>>6;                 // 4 groups of 8 segments
    float a1=0.f,a2=0.f;
    #pragma unroll 2
    for(int g=tg*8;g<tg*8+8;g++){
      a1+=statsP[((size_t)(b*32+g)*64+tc)*2+0];
      a2+=statsP[((size_t)(b*32+g)*64+tc)*2+1];
    }
    red1[tid]=a1; red2[tid]=a2;
  }
  __syncthreads();
  if(tid<64){
    float s1=red1[tid]+red1[tid+64]+red1[tid+128]+red1[tid+192];
    float s2=red2[tid]+red2[tid+64]+red2[tid+128]+red2[tid+192];
    float mu=s1*(1.0f/N_);
    float var=s2*(1.0f/N_)-mu*mu;
    mean[tid]=mu; rstd[tid]=rsqrtf(var+1e-5f);
  }
  __syncthreads();
  const float4* hr4=(const float4*)(x+((size_t)(b*N_+n))*64);
  float4 acc[8];
  #pragma unroll
  for(int q=0;q<8;q++) acc[q]=make_float4(0.f,0.f,0.f,0.f);
  #pragma unroll
  for(int ch=0;ch<4;ch++){
    float4 t[4];
    #pragma unroll
    for(int j=0;j<4;j++) t[j]=hr4[ch*4+j];
    #pragma unroll
    for(int j=0;j<4;j++){
      int d0=ch*16+j*4;
      float hv[4];
      hv[0]=(t[j].x-mean[d0+0])*rstd[d0+0];
      hv[1]=(t[j].y-mean[d0+1])*rstd[d0+1];
      hv[2]=(t[j].z-mean[d0+2])*rstd[d0+2];
      hv[3]=(t[j].w-mean[d0+3])*rstd[d0+3];
      #pragma unroll
      for(int dd=0;dd<4;dd++){
        float hvv=hv[dd];
        #pragma unroll
        for(int q=0;q<8;q++){
          float4 wv=w4[(h*64+d0+dd)*8+q];
          acc[q].x+=hvv*wv.x;acc[q].y+=hvv*wv.y;acc[q].z+=hvv*wv.z;acc[q].w+=hvv*wv.w;
        }
      }
    }
  }
  float ssv=0.f,sdv=0.f;
  #pragma unroll
  for(int q=0;q<8;q++){
    float4 a1=av4[h*8+q],a2=av4[32+h*8+q];
    ssv+=acc[q].x*a1.x+acc[q].y*a1.y+acc[q].z*a1.z+acc[q].w*a1.w;
    sdv+=acc[q].x*a2.x+acc[q].y*a2.y+acc[q].z*a2.z+acc[q].w*a2.w;
  }
  int p=b*4+h;
  float4* o4=(float4*)(hp+((size_t)p*N_+n)*32);
  #pragma unroll
  for(int q=0;q<8;q++) o4[q]=acc[q];
  ss[(size_t)p*N_+n]=ssv; sd[(size_t)p*N_+n]=sdv;
}

// ---------- layer1 projection; q4 wave-uniform; spread stats reduce ----------
__global__ void __launch_bounds__(256) kproj1(
                       const float* __restrict__ x, const float* __restrict__ statsP,
                       const float* __restrict__ w1, const float* __restrict__ asrc,
                       const float* __restrict__ adst, float* __restrict__ hp,
                       float* __restrict__ ss, float* __restrict__ sd){
  __shared__ float4 w4[2048];
  __shared__ float wa[128],wd[128],mean[128],rstd[128];
  __shared__ float red1[256],red2[256];
  int tid=threadIdx.x;
  const float4* wg=(const float4*)w1;
  for(int i=tid;i<2048;i+=256) w4[i]=wg[i];
  int gid=blockIdx.x*256+tid;
  int b=gid>>14, q4=(gid>>12)&3, n=gid&4095;  // wave-uniform q4; b block-uniform
  {
    int tc=tid&127, tg=tid>>7;                // 2 groups of 16 segments
    float a1=0.f,a2=0.f;
    #pragma unroll 4
    for(int g=tg*16;g<tg*16+16;g++){
      a1+=statsP[((size_t)(b*32+g)*128+tc)*2+0];
      a2+=statsP[((size_t)(b*32+g)*128+tc)*2+1];
    }
    red1[tid]=a1; red2[tid]=a2;
  }
  __syncthreads();
  if(tid<128){
    float s1a=0.f,s2a=0.f;
    for(int k=0;k<64;k++){float wv=w1[tid*64+k];s1a+=wv*asrc[k];s2a+=wv*adst[k];}
    wa[tid]=s1a;wd[tid]=s2a;
    float s1=red1[tid]+red1[tid+128];
    float s2=red2[tid]+red2[tid+128];
    float mu=s1*(1.0f/N_);
    float var=s2*(1.0f/N_)-mu*mu;
    mean[tid]=mu; rstd[tid]=rsqrtf(var+1e-5f);
  }
  __syncthreads();
  const float4* hr4=(const float4*)(x+((size_t)(b*N_+n))*128);
  float4 acc[4];
  #pragma unroll
  for(int q=0;q<4;q++) acc[q]=make_float4(0.f,0.f,0.f,0.f);
  float s1=0.f,s2=0.f;
  #pragma unroll
  for(int ch=0;ch<8;ch++){
    float4 t[4];
    #pragma unroll
    for(int j=0;j<4;j++) t[j]=hr4[ch*4+j];
    #pragma unroll
    for(int j=0;j<4;j++){
      int d0=ch*16+j*4;
      float hv[4];
      hv[0]=(t[j].x-mean[d0+0])*rstd[d0+0];
      hv[1]=(t[j].y-mean[d0+1])*rstd[d0+1];
      hv[2]=(t[j].z-mean[d0+2])*rstd[d0+2];
      hv[3]=(t[j].w-mean[d0+3])*rstd[d0+3];
      #pragma unroll
      for(int dd=0;dd<4;dd++){
        float hvv=hv[dd]; int d=d0+dd;
        s1+=hvv*wa[d]; s2+=hvv*wd[d];
        #pragma unroll
        for(int q=0;q<4;q++){
          float4 wv=w4[d*16+q4*4+q];
          acc[q].x+=hvv*wv.x;acc[q].y+=hvv*wv.y;acc[q].z+=hvv*wv.z;acc[q].w+=hvv*wv.w;
        }
      }
    }
  }
  float4* o4=(float4*)(hp+((size_t)(b*N_+n))*64+q4*16);
  #pragma unroll
  for(int q=0;q<4;q++) o4[q]=acc[q];
  if(q4==0){
    ss[(size_t)b*N_+n]=s1;sd[(size_t)b*N_+n]=s2;
  }
}

// ---------- sort runs of 1024 (packed u64 = key<<32 | orig_idx) --------------
__global__ void __launch_bounds__(256) ksort_runs(const float* __restrict__ sdst,
                                                  unsigned long long* __restrict__ runs){
  __shared__ unsigned long long sm[1024];
  int p=blockIdx.x>>2, run=blockIdx.x&3;
  int tid=threadIdx.x;
  const float* s=sdst+(size_t)p*N_+run*1024;
  for(int l=tid;l<1024;l+=256){
    unsigned key=f2s(s[l]);
    sm[l]=((unsigned long long)key<<32)|(unsigned)(run*1024+l);
  }
  for(unsigned k=2;k<=1024u;k<<=1)
    for(unsigned j=k>>1;j>0;j>>=1){
      __syncthreads();
      for(unsigned t=tid;t<512u;t+=256u){
        unsigned i=((t&~(j-1))<<1)|(t&(j-1));
        unsigned q=i|j;
        bool up=((i&k)==0);
        unsigned long long a=sm[i],b=sm[q];
        if((a>b)==up){sm[i]=b;sm[q]=a;}
      }
    }
  __syncthreads();
  unsigned long long* rg=runs+(size_t)p*N_+run*1024;
  for(int l=tid;l<1024;l+=256) rg[l]=sm[l];
}

// ---------- merge 4 sorted runs by rank (binary search in LDS) ---------------
__global__ void __launch_bounds__(1024) kmerge(const unsigned long long* __restrict__ runs,
    float* __restrict__ sv, unsigned* __restrict__ perm,
    float* __restrict__ eP, float* __restrict__ eN){
  __shared__ unsigned long long sm[4096];
  int p=blockIdx.x>>2, cg=blockIdx.x&3;
  int tid=threadIdx.x;
  const unsigned long long* rg=runs+(size_t)p*N_;
  for(int l=tid;l<4096;l+=1024) sm[l]=rg[l];
  __syncthreads();
  unsigned long long e=sm[cg*1024+tid];
  int rank=tid;
  #pragma unroll
  for(int o=0;o<4;o++){
    if(o==cg) continue;
    const unsigned long long* base=sm+o*1024;
    int lo=0,hi=1024;
    while(lo<hi){int mid=(lo+hi)>>1; if(base[mid]<e) lo=mid+1; else hi=mid;}
    rank+=lo;
  }
  unsigned long long mk=sm[1023];
  if(sm[2047]>mk) mk=sm[2047];
  if(sm[3071]>mk) mk=sm[3071];
  if(sm[4095]>mk) mk=sm[4095];
  float m=s2f((unsigned)(mk>>32));
  float v=s2f((unsigned)(e>>32));
  size_t o=(size_t)p*N_+rank;
  sv[o]=v;
  perm[o]=(unsigned)(e&0xffffffffu);
  eP[o]=expf(v-m);
  eN[o]=expf(0.2f*(v-m));
}

// ---------- absolute scalar count prefixes per p (block scan) ----------------
__global__ void __launch_bounds__(1024) kcounts(const float* __restrict__ eP,
    const float* __restrict__ eN, float* __restrict__ CPP, float* __restrict__ CPN){
  __shared__ float sp[1024],sn[1024];
  int p=blockIdx.x, t=threadIdx.x;
  float4 e4=((const float4*)(eP+(size_t)p*N_))[t];
  float4 n4=((const float4*)(eN+(size_t)p*N_))[t];
  float lp=e4.x+e4.y+e4.z+e4.w;
  float ln=n4.x+n4.y+n4.z+n4.w;
  sp[t]=lp; sn[t]=ln; __syncthreads();
  for(int off=1;off<1024;off<<=1){
    float vp=(t>=off)?sp[t-off]:0.f;
    float vn=(t>=off)?sn[t-off]:0.f;
    __syncthreads();
    sp[t]+=vp; sn[t]+=vn;
    __syncthreads();
  }
  float bp=sp[t]-lp, bn=sn[t]-ln;   // exclusive base for this thread's 4
  size_t o=(size_t)p*4097+t*4;
  float a=bp;          CPP[o+0]=a;
  a+=e4.x;             CPP[o+1]=a;
  a+=e4.y;             CPP[o+2]=a;
  a+=e4.z;             CPP[o+3]=a;
  a=bn;                CPN[o+0]=a;
  a+=n4.x;             CPN[o+1]=a;
  a+=n4.y;             CPN[o+2]=a;
  a+=n4.z;             CPN[o+3]=a;
  if(t==1023){CPP[(size_t)p*4097+4096]=sp[1023]; CPN[(size_t)p*4097+4096]=sn[1023];}
}

// ---------- layer0 relative tables: 2 chunks per wave, width-32 rows ---------
__global__ void __launch_bounds__(256) ktables0(const unsigned* __restrict__ perm,
    const float* __restrict__ eP, const float* __restrict__ eN,
    const float* __restrict__ hp, float* __restrict__ TPP, float* __restrict__ TPN,
    float* __restrict__ rawP, float* __restrict__ rawN){
  int gw=(blockIdx.x*256+threadIdx.x)>>6;   // 0..2047
  int lane=threadIdx.x&63, half=lane>>5, ch=lane&31;
  int cglob=gw*2+half;
  int p=cglob>>8, c=cglob&255;
  float aP=0.f,aN=0.f;
  for(int q=0;q<16;q++){
    int r=c*16+q;
    size_t ro=(size_t)p*N_+r;
    float ep=eP[ro],en=eN[ro];
    unsigned pr=perm[ro];
    float hv=hp[((size_t)p*N_+pr)*32+ch];
    size_t to=((size_t)p*4097+r)*32+ch;
    TPP[to]=aP; TPN[to]=aN;
    aP+=ep*hv; aN+=en*hv;
  }
  size_t bo=((size_t)p*256+c)*32+ch;
  rawP[bo]=aP; rawN[bo]=aN;
}

// ---------- layer1 relative tables: wave per chunk, width-64 rows ------------
__global__ void __launch_bounds__(256) ktables1(const unsigned* __restrict__ perm,
    const float* __restrict__ eP, const float* __restrict__ eN,
    const float* __restrict__ hp, float* __restrict__ TPP, float* __restrict__ TPN,
    float* __restrict__ rawP, float* __restrict__ rawN){
  int wid=(blockIdx.x*256+threadIdx.x)>>6;   // 0..1023
  int lane=threadIdx.x&63;
  int p=wid>>8, c=wid&255;
  float aP=0.f,aN=0.f;
  for(int q=0;q<16;q++){
    int r=c*16+q;
    size_t ro=(size_t)p*N_+r;
    float ep=eP[ro],en=eN[ro];
    unsigned pr=perm[ro];
    float hv=hp[((size_t)p*N_+pr)*64+lane];
    size_t to=((size_t)p*4097+r)*64+lane;
    TPP[to]=aP; TPN[to]=aN;
    aP+=ep*hv; aN+=en*hv;
  }
  size_t bo=((size_t)p*256+c)*64+lane;
  rawP[bo]=aP; rawN[bo]=aN;
}

// ---------- scan chunk sums -> bases; totals -> table row 4096 ---------------
template<int D>
__global__ void __launch_bounds__(256) kscan(const float* __restrict__ rawP,
    const float* __restrict__ rawN, float* __restrict__ bP, float* __restrict__ bN,
    float* __restrict__ TPP, float* __restrict__ TPN){
  extern __shared__ float sm[];   // 256*D
  int p=blockIdx.x, tid=threadIdx.x;
  for(int pass=0;pass<2;pass++){
    const float* src=pass?rawN:rawP;
    float* dst=pass?bN:bP;
    float* tp=pass?TPN:TPP;
    __syncthreads();
    for(int i=tid;i<256*D;i+=256){
      sm[i]=src[(size_t)p*256*D+i];
    }
    __syncthreads();
    if(tid<D){
      float r=0.f;
      for(int c=0;c<256;c++){
        dst[((size_t)p*257+c)*D+tid]=r;
        r+=sm[c*D+tid];
      }
      dst[((size_t)p*257+256)*D+tid]=0.f;      // base for lo==4096
      tp[((size_t)p*4097+4096)*D+tid]=r;       // absolute channel totals
    }
  }
}

// ---------- layer0 row eval: 2 rows per wave, 3-level ballot search ----------
__global__ void __launch_bounds__(256) keval0(const float* __restrict__ ss,
                       const float* __restrict__ sv,
                       const float* __restrict__ bP, const float* __restrict__ bN,
                       const float* __restrict__ TPP, const float* __restrict__ TPN,
                       const float* __restrict__ CPP, const float* __restrict__ CPN,
                       const float* __restrict__ bias, float* __restrict__ out){
  int gw=(blockIdx.x*256+threadIdx.x)>>6;   // 0..32767
  int lane=threadIdx.x&63, half=lane>>5, ch=lane&31;
  int row=gw*2+half;
  int p=row>>12, i=row&4095;
  int b=p>>2, h=p&3;
  const float* svp=sv+(size_t)p*N_;
  float ssrc=ss[(size_t)p*N_+i];
  float m=svp[4095];
  float xx=ssrc+m;
  float M=xx>0.f?xx:0.2f*xx;
  float fpos=expf(xx-M),fneg=expf(0.2f*xx-M);
  float th=-ssrc;
  // level1: 32 samples of block-last (stride 128)
  float s1v=svp[ch*128+127];
  unsigned long long bal=__ballot(s1v<=th);
  int c1=half?(int)__popcll(bal>>32):(int)__popcll(bal&0xFFFFFFFFull);
  int lo;
  if(c1>=32){ lo=4096; }
  else{
    float s2v=svp[c1*128+ch*4+3];
    unsigned long long bal2=__ballot(s2v<=th);
    int c2=half?(int)__popcll(bal2>>32):(int)__popcll(bal2&0xFFFFFFFFull);
    int base=c1*128+c2*4;
    float4 qv=*((const float4*)(svp+base));
    int c3=(qv.x<=th)+(qv.y<=th)+(qv.z<=th)+(qv.w<=th);
    lo=base+c3;
  }
  int c=lo>>4;
  float relP=TPP[((size_t)p*4097+lo)*32+ch];
  float relN=TPN[((size_t)p*4097+lo)*32+ch];
  float baP=bP[((size_t)p*257+c)*32+ch];
  float baN=bN[((size_t)p*257+c)*32+ch];
  float tot=TPP[((size_t)p*4097+4096)*32+ch];
  float CPl=CPP[(size_t)p*4097+lo];
  float CNl=CPN[(size_t)p*4097+lo];
  float CT =CPP[(size_t)p*4097+4096];
  float denom=fpos*(CT-CPl)+fneg*CNl;
  float v=fpos*(tot-(baP+relP))+fneg*(baN+relN);
  float r=v/denom+bias[ch];
  r=r>0.f?r:expm1f(r);
  out[((size_t)(b*N_+i))*128+h*32+ch]=r;
}

// ---------- layer1 row eval: wave per row, width-64 --------------------------
__global__ void __launch_bounds__(256) keval1(const float* __restrict__ ss,
                       const float* __restrict__ sv,
                       const float* __restrict__ bP, const float* __restrict__ bN,
                       const float* __restrict__ TPP, const float* __restrict__ TPN,
                       const float* __restrict__ CPP, const float* __restrict__ CPN,
                       const float* __restrict__ bias, float* __restrict__ out){
  int wid=(blockIdx.x*256+threadIdx.x)>>6;   // p*4096+i
  int lane=threadIdx.x&63;
  int p=wid>>12, i=wid&4095;
  const float* svp=sv+(size_t)p*N_;
  float ssrc=ss[(size_t)p*N_+i];
  float m=svp[4095];
  float xx=ssrc+m;
  float M=xx>0.f?xx:0.2f*xx;
  float fpos=expf(xx-M),fneg=expf(0.2f*xx-M);
  float th=-ssrc;
  float s1v=svp[lane*64+63];
  int c1=(int)__popcll(__ballot(s1v<=th));
  int lo;
  if(c1>=64){ lo=4096; }
  else{
    float s2v=svp[c1*64+lane];
    lo=c1*64+(int)__popcll(__ballot(s2v<=th));
  }
  int c=lo>>4;
  float relP=TPP[((size_t)p*4097+lo)*64+lane];
  float relN=TPN[((size_t)p*4097+lo)*64+lane];
  float baP=bP[((size_t)p*257+c)*64+lane];
  float baN=bN[((size_t)p*257+c)*64+lane];
  float tot=TPP[((size_t)p*4097+4096)*64+lane];
  float CPl=CPP[(size_t)p*4097+lo];
  float CNl=CPN[(size_t)p*4097+lo];
  float CT =CPP[(size_t)p*4097+4096];
  float denom=fpos*(CT-CPl)+fneg*CNl;
  float v=fpos*(tot-(baP+relP))+fneg*(baN+relN);
  out[((size_t)p*N_+i)*64+lane]=v/denom+bias[lane];
}

extern "C" void kernel_launch(void* const* d_in, const int* in_sizes, int n_in,
                              void* d_out, int out_size, void* d_ws, size_t ws_size,
                              hipStream_t stream) {
  const float* x  =(const float*)d_in[0];
  const float* w0 =(const float*)d_in[1];
  const float* as0=(const float*)d_in[2];
  const float* ad0=(const float*)d_in[3];
  const float* b0 =(const float*)d_in[4];
  const float* w1 =(const float*)d_in[5];
  const float* as1=(const float*)d_in[6];
  const float* ad1=(const float*)d_in[7];
  const float* b1 =(const float*)d_in[8];
  float* ws=(float*)d_ws;
  float* out=(float*)d_out;

  float* s0p = ws+OFF_S0P;
  float* s1p = ws+OFF_S1P;
  float* hp0 = ws+OFF_HP0;
  float* elu = ws+OFF_ELU;
  float* ss0 = ws+OFF_SS0;  float* sd0 = ws+OFF_SD0;
  unsigned long long* runs0=(unsigned long long*)(ws+OFF_RUNS0);
  float* sv0 = ws+OFF_SV0;
  unsigned* pm0=(unsigned*)(ws+OFF_PM0);
  float* eP0 = ws+OFF_EP0;  float* eN0 = ws+OFF_EN0;
  float* cP0 = ws+OFF_CPP0; float* cN0 = ws+OFF_CPN0;
  float* rP0 = ws+OFF_RAWP0; float* rN0 = ws+OFF_RAWN0;
  float* bP0 = ws+OFF_BP0;  float* bN0 = ws+OFF_BN0;
  float* tP0 = ws+OFF_TPP0; float* tN0 = ws+OFF_TPN0;
  float* hp1 = ws+OFF_HP1;
  float* ss1 = ws+OFF_SS1;  float* sd1 = ws+OFF_SD1;
  unsigned long long* runs1=(unsigned long long*)(ws+OFF_RUNS1);
  float* sv1 = ws+OFF_SV1;
  unsigned* pm1=(unsigned*)(ws+OFF_PM1);
  float* eP1 = ws+OFF_EP1;  float* eN1 = ws+OFF_EN1;
  float* cP1 = ws+OFF_CPP1; float* cN1 = ws+OFF_CPN1;
  float* rP1 = ws+OFF_RAWP1; float* rN1 = ws+OFF_RAWN1;
  float* bP1 = ws+OFF_BP1;  float* bN1 = ws+OFF_BN1;
  float* tP1 = ws+OFF_TPP1; float* tN1 = ws+OFF_TPN1;

  // ---- layer 0 ----
  kstats<64><<<128,256,0,stream>>>(x,s0p);
  kproj0<<<256,256,0,stream>>>(x,s0p,w0,as0,ad0,hp0,ss0,sd0);
  ksort_runs<<<64,256,0,stream>>>(sd0,runs0);
  kmerge<<<64,1024,0,stream>>>(runs0,sv0,pm0,eP0,eN0);
  kcounts<<<16,1024,0,stream>>>(eP0,eN0,cP0,cN0);
  ktables0<<<512,256,0,stream>>>(pm0,eP0,eN0,hp0,tP0,tN0,rP0,rN0);
  kscan<32><<<16,256,256*32*4,stream>>>(rP0,rN0,bP0,bN0,tP0,tN0);
  keval0<<<8192,256,0,stream>>>(ss0,sv0,bP0,bN0,tP0,tN0,cP0,cN0,b0,elu);
  // ---- layer 1 ----
  kstats<128><<<128,256,0,stream>>>(elu,s1p);
  kproj1<<<256,256,0,stream>>>(elu,s1p,w1,as1,ad1,hp1,ss1,sd1);
  ksort_runs<<<16,256,0,stream>>>(sd1,runs1);
  kmerge<<<16,1024,0,stream>>>(runs1,sv1,pm1,eP1,eN1);
  kcounts<<<4,1024,0,stream>>>(eP1,eN1,cP1,cN1);
  ktables1<<<256,256,0,stream>>>(pm1,eP1,eN1,hp1,tP1,tN1,rP1,rN1);
  kscan<64><<<4,256,256*64*4,stream>>>(rP1,rN1,bP1,bN1,tP1,tN1);
  keval1<<<4096,256,0,stream>>>(ss1,sv1,bP1,bN1,tP1,tN1,cP1,cN1,b1,out);
}